// Round 1
// baseline (2992.181 us; speedup 1.0000x reference)
//
#include <hip/hip_runtime.h>
#include <math.h>

#define NB   4
#define NG0  2500
#define ETOT 100000
#define CH   512
#define NEGS 0.2f

// N per layer in: 10000, 7000, 4900, 3432 ; after last pool: 2404
static const int h_Ns[5]  = {10000, 7000, 4900, 3432, 2404};
static const int h_ngs[4] = {2500, 1750, 1225, 858};
static const int h_ks[4]  = {1750, 1225, 858, 601};

// ---------------- edge init ----------------
__global__ void k_edge_init(const int* __restrict__ ei, int* src, int* dst, int* mask) {
    int e = blockIdx.x * blockDim.x + threadIdx.x;
    if (e < ETOT) { src[e] = ei[e]; dst[e] = ei[ETOT + e]; mask[e] = 1; }
}

// ---------------- CSR build ----------------
__global__ void k_hist(const int* __restrict__ dst, const int* __restrict__ mask, int* cnt) {
    int e = blockIdx.x * blockDim.x + threadIdx.x;
    if (e < ETOT && mask[e]) atomicAdd(&cnt[dst[e]], 1);
}

// single block: exclusive scan of cnt[0..N) -> rowptr[0..N], cnt becomes cursor copy
__global__ __launch_bounds__(1024) void k_scan(int* cnt, int* rowptr, int N) {
    __shared__ int lds[1024];
    __shared__ int s_carry;
    int t = threadIdx.x;
    if (t == 0) s_carry = 0;
    __syncthreads();
    for (int base = 0; base < N; base += 1024) {
        int i = base + t;
        int v = (i < N) ? cnt[i] : 0;
        lds[t] = v;
        __syncthreads();
        for (int offn = 1; offn < 1024; offn <<= 1) {
            int add = (t >= offn) ? lds[t - offn] : 0;
            __syncthreads();
            lds[t] += add;
            __syncthreads();
        }
        int excl = lds[t] - v;
        if (i < N) { int r = s_carry + excl; rowptr[i] = r; cnt[i] = r; }
        __syncthreads();
        if (t == 1023) s_carry += lds[1023];
        __syncthreads();
    }
    if (t == 0) rowptr[N] = s_carry;
}

__global__ void k_scatter(const int* __restrict__ dst, const int* __restrict__ mask,
                          int* cursor, int* seid) {
    int e = blockIdx.x * blockDim.x + threadIdx.x;
    if (e < ETOT && mask[e]) { int p = atomicAdd(&cursor[dst[e]], 1); seid[p] = e; }
}

// ---------------- GEMM: out[row, ooff+col] = A[row,:512] @ W[:512, col<1024] + bias ----------------
__global__ __launch_bounds__(256) void k_gemm(const float* __restrict__ A, const float* __restrict__ W,
                                              const float* __restrict__ bias, float* __restrict__ out,
                                              int M, int ldo, int ooff) {
    __shared__ float As[64][17];
    __shared__ float Bs[16][68];
    int tid = threadIdx.x;
    int rowBase = blockIdx.x * 64;
    int colBase = blockIdx.y * 64;
    int tr = tid >> 4, tc = tid & 15;
    float acc[4][4];
#pragma unroll
    for (int a = 0; a < 4; ++a)
#pragma unroll
        for (int b = 0; b < 4; ++b) acc[a][b] = 0.f;
    int ar = tid >> 2, akc = (tid & 3) * 4;
    int br = tid >> 4, bc = (tid & 15) * 4;
    for (int k0 = 0; k0 < 512; k0 += 16) {
        int arow = rowBase + ar;
        if (arow < M) {
            const float4 v = *(const float4*)(A + (size_t)arow * 512 + k0 + akc);
            As[ar][akc] = v.x; As[ar][akc + 1] = v.y; As[ar][akc + 2] = v.z; As[ar][akc + 3] = v.w;
        } else {
            As[ar][akc] = 0.f; As[ar][akc + 1] = 0.f; As[ar][akc + 2] = 0.f; As[ar][akc + 3] = 0.f;
        }
        const float4 w = *(const float4*)(W + (size_t)(k0 + br) * 1024 + colBase + bc);
        Bs[br][bc] = w.x; Bs[br][bc + 1] = w.y; Bs[br][bc + 2] = w.z; Bs[br][bc + 3] = w.w;
        __syncthreads();
#pragma unroll
        for (int kk = 0; kk < 16; ++kk) {
            float a0 = As[tr * 4 + 0][kk], a1 = As[tr * 4 + 1][kk], a2 = As[tr * 4 + 2][kk], a3 = As[tr * 4 + 3][kk];
            float b0 = Bs[kk][tc * 4 + 0], b1v = Bs[kk][tc * 4 + 1], b2v = Bs[kk][tc * 4 + 2], b3v = Bs[kk][tc * 4 + 3];
            acc[0][0] += a0 * b0; acc[0][1] += a0 * b1v; acc[0][2] += a0 * b2v; acc[0][3] += a0 * b3v;
            acc[1][0] += a1 * b0; acc[1][1] += a1 * b1v; acc[1][2] += a1 * b2v; acc[1][3] += a1 * b3v;
            acc[2][0] += a2 * b0; acc[2][1] += a2 * b1v; acc[2][2] += a2 * b2v; acc[2][3] += a2 * b3v;
            acc[3][0] += a3 * b0; acc[3][1] += a3 * b1v; acc[3][2] += a3 * b2v; acc[3][3] += a3 * b3v;
        }
        __syncthreads();
    }
#pragma unroll
    for (int jr = 0; jr < 4; ++jr) {
        int row = rowBase + tr * 4 + jr;
        if (row < M) {
            int col = colBase + tc * 4;
            float4 r;
            r.x = acc[jr][0] + bias[col + 0];
            r.y = acc[jr][1] + bias[col + 1];
            r.z = acc[jr][2] + bias[col + 2];
            r.w = acc[jr][3] + bias[col + 3];
            *(float4*)(out + (size_t)row * ldo + ooff + col) = r;
        }
    }
}

// ---------------- edge attention logits (one wave per edge or self-loop) ----------------
__global__ __launch_bounds__(256) void k_logits(const float* __restrict__ xlr,
                                                const int* __restrict__ src, const int* __restrict__ dst,
                                                const int* __restrict__ mask,
                                                const float* __restrict__ att,
                                                float* __restrict__ logits, int N) {
    int wid = (blockIdx.x * blockDim.x + threadIdx.x) >> 6;
    int lane = threadIdx.x & 63;
    int items = ETOT + N;
    if (wid >= items) return;
    int s, d;
    if (wid < ETOT) {
        if (!mask[wid]) return;
        s = src[wid]; d = dst[wid];
    } else {
        s = d = wid - ETOT;
    }
    const float* xl = xlr + (size_t)s * 2048;
    const float* xr = xlr + (size_t)d * 2048 + 1024;
    float acc0 = 0.f, acc1 = 0.f;
    int c0 = lane * 8;
#pragma unroll
    for (int h = 0; h < 2; ++h) {
        const float* pa = xl + h * 512 + c0;
        const float* pb = xr + h * 512 + c0;
        const float* pt = att + h * 512 + c0;
        float a = 0.f;
#pragma unroll
        for (int j = 0; j < 2; ++j) {
            float4 va = *(const float4*)(pa + j * 4);
            float4 vb = *(const float4*)(pb + j * 4);
            float4 vt = *(const float4*)(pt + j * 4);
            float e0 = va.x + vb.x; e0 = e0 > 0.f ? e0 : NEGS * e0; a += e0 * vt.x;
            float e1 = va.y + vb.y; e1 = e1 > 0.f ? e1 : NEGS * e1; a += e1 * vt.y;
            float e2 = va.z + vb.z; e2 = e2 > 0.f ? e2 : NEGS * e2; a += e2 * vt.z;
            float e3 = va.w + vb.w; e3 = e3 > 0.f ? e3 : NEGS * e3; a += e3 * vt.w;
        }
        if (h == 0) acc0 = a; else acc1 = a;
    }
#pragma unroll
    for (int offn = 32; offn > 0; offn >>= 1) {
        acc0 += __shfl_xor(acc0, offn, 64);
        acc1 += __shfl_xor(acc1, offn, 64);
    }
    if (lane == 0) { logits[(size_t)wid * 2] = acc0; logits[(size_t)wid * 2 + 1] = acc1; }
}

// ---------------- per-dst softmax + weighted aggregate + head-mean + bias + relu ----------------
__global__ __launch_bounds__(256) void k_aggregate(const float* __restrict__ xlr,
                                                   const float* __restrict__ logits,
                                                   const int* __restrict__ rowptr, const int* __restrict__ seid,
                                                   const int* __restrict__ src,
                                                   const float* __restrict__ bias,
                                                   float* __restrict__ out, int N) {
    int d = blockIdx.x;
    if (d >= N) return;
    int rs = rowptr[d], re = rowptr[d + 1];
    int t = threadIdx.x;
    int selfe = ETOT + d;
    // phase 1: max + denom per head (redundant per thread; broadcast loads)
    float sl0 = logits[(size_t)selfe * 2], sl1 = logits[(size_t)selfe * 2 + 1];
    float mx0 = sl0, mx1 = sl1;
    for (int e = rs; e < re; ++e) {
        int eid = seid[e];
        mx0 = fmaxf(mx0, logits[(size_t)eid * 2]);
        mx1 = fmaxf(mx1, logits[(size_t)eid * 2 + 1]);
    }
    float den0 = __expf(sl0 - mx0), den1 = __expf(sl1 - mx1);
    for (int e = rs; e < re; ++e) {
        int eid = seid[e];
        den0 += __expf(logits[(size_t)eid * 2] - mx0);
        den1 += __expf(logits[(size_t)eid * 2 + 1] - mx1);
    }
    float invd0 = 1.f / fmaxf(den0, 1e-16f);
    float invd1 = 1.f / fmaxf(den1, 1e-16f);
    // phase 2: accumulate alpha * xl[s]
    int elem = t * 4;
    int h = t >> 7;
    float mxh = h ? mx1 : mx0;
    float invdh = h ? invd1 : invd0;
    float ax = 0.f, ay = 0.f, az = 0.f, aw = 0.f;
    {
        float al = __expf((h ? sl1 : sl0) - mxh) * invdh;
        float4 v = *(const float4*)(xlr + (size_t)d * 2048 + elem);
        ax += al * v.x; ay += al * v.y; az += al * v.z; aw += al * v.w;
    }
    for (int e = rs; e < re; ++e) {
        int eid = seid[e];
        int s = src[eid];
        float al = __expf(logits[(size_t)eid * 2 + h] - mxh) * invdh;
        float4 v = *(const float4*)(xlr + (size_t)s * 2048 + elem);
        ax += al * v.x; ay += al * v.y; az += al * v.z; aw += al * v.w;
    }
    __shared__ float lds[1024];
    lds[elem + 0] = ax; lds[elem + 1] = ay; lds[elem + 2] = az; lds[elem + 3] = aw;
    __syncthreads();
    if (t < 128) {
        int c = t * 4;
        float4 bb = *(const float4*)(bias + c);
        float4 r;
        r.x = fmaxf(0.5f * (lds[c + 0] + lds[512 + c + 0]) + bb.x, 0.f);
        r.y = fmaxf(0.5f * (lds[c + 1] + lds[512 + c + 1]) + bb.y, 0.f);
        r.z = fmaxf(0.5f * (lds[c + 2] + lds[512 + c + 2]) + bb.z, 0.f);
        r.w = fmaxf(0.5f * (lds[c + 3] + lds[512 + c + 3]) + bb.w, 0.f);
        *(float4*)(out + (size_t)d * 512 + c) = r;
    }
}

// ---------------- SAG score: GraphConv (agg@Wrel + brel + x@Wroot) ----------------
__global__ __launch_bounds__(64) void k_score(const float* __restrict__ x,
                                              const int* __restrict__ rowptr, const int* __restrict__ seid,
                                              const int* __restrict__ src,
                                              const float* __restrict__ Wrel, const float* __restrict__ Wroot,
                                              const float* __restrict__ brel_p,
                                              float* __restrict__ score, int N) {
    int d = blockIdx.x;
    if (d >= N) return;
    int lane = threadIdx.x;
    int c0 = lane * 8;
    float agg[8];
#pragma unroll
    for (int j = 0; j < 8; ++j) agg[j] = 0.f;
    int rs = rowptr[d], re = rowptr[d + 1];
    for (int e = rs; e < re; ++e) {
        int s = src[seid[e]];
        const float* xs = x + (size_t)s * 512 + c0;
#pragma unroll
        for (int j = 0; j < 8; ++j) agg[j] += xs[j];
    }
    const float* xd = x + (size_t)d * 512 + c0;
    float p = 0.f;
#pragma unroll
    for (int j = 0; j < 8; ++j) p += agg[j] * Wrel[c0 + j] + xd[j] * Wroot[c0 + j];
#pragma unroll
    for (int offn = 32; offn > 0; offn >>= 1) p += __shfl_xor(p, offn, 64);
    if (lane == 0) score[d] = p + brel_p[0];
}

// ---------------- per-graph top-k via bitonic sort in LDS ----------------
__global__ __launch_bounds__(1024) void k_topk(const float* __restrict__ score, int ng, int k,
                                               int* __restrict__ newidx, int* __restrict__ sel_old,
                                               float* __restrict__ sel_scale) {
    int b = blockIdx.x;
    __shared__ float v[4096];
    __shared__ int ix[4096];
    int t = threadIdx.x;
    for (int i = t; i < 4096; i += 1024) {
        if (i < ng) {
            v[i] = score[b * ng + i];
            ix[i] = i;
            newidx[b * ng + i] = -1;
        } else {
            v[i] = -INFINITY;
            ix[i] = 0x7fffffff;
        }
    }
    __syncthreads();
    for (int size = 2; size <= 4096; size <<= 1) {
        for (int stride = size >> 1; stride > 0; stride >>= 1) {
            for (int i = t; i < 4096; i += 1024) {
                int j = i ^ stride;
                if (j > i) {
                    bool desc = ((i & size) == 0);
                    float vi = v[i], vj = v[j];
                    int xi = ix[i], xj = ix[j];
                    bool sw = desc ? (vi < vj || (vi == vj && xi > xj))
                                   : (vi > vj || (vi == vj && xi < xj));
                    if (sw) { v[i] = vj; v[j] = vi; ix[i] = xj; ix[j] = xi; }
                }
            }
            __syncthreads();
        }
    }
    for (int j = t; j < k; j += 1024) {
        int oldg = b * ng + ix[j];
        int newg = b * k + j;
        newidx[oldg] = newg;
        sel_old[newg] = oldg;
        sel_scale[newg] = tanhf(v[j]);
    }
}

// ---------------- pool gather + tanh scale ----------------
__global__ __launch_bounds__(128) void k_pool(const float* __restrict__ x, const int* __restrict__ sel_old,
                                              const float* __restrict__ sel_scale, float* __restrict__ xn) {
    int nn = blockIdx.x;
    int so = sel_old[nn];
    float sc = sel_scale[nn];
    int c = threadIdx.x * 4;
    float4 vv = *(const float4*)(x + (size_t)so * 512 + c);
    vv.x *= sc; vv.y *= sc; vv.z *= sc; vv.w *= sc;
    *(float4*)(xn + (size_t)nn * 512 + c) = vv;
}

// ---------------- edge remap ----------------
__global__ void k_remap(int* src, int* dst, int* mask, const int* __restrict__ newidx) {
    int e = blockIdx.x * blockDim.x + threadIdx.x;
    if (e >= ETOT) return;
    if (!mask[e]) return;
    int ns = newidx[src[e]];
    int nd = newidx[dst[e]];
    if (ns >= 0 && nd >= 0) { src[e] = ns; dst[e] = nd; }
    else mask[e] = 0;
}

// ---------------- readout: per-graph max & mean, accumulated across layers ----------------
__global__ __launch_bounds__(256) void k_readout(const float* __restrict__ x, int k, float* __restrict__ readout) {
    int b = blockIdx.x;
    int c = blockIdx.y * 256 + threadIdx.x;
    float mx = -1e30f, sm = 0.f;
    for (int j = 0; j < k; ++j) {
        float vv = x[((size_t)(b * k + j)) * 512 + c];
        mx = fmaxf(mx, vv);
        sm += vv;
    }
    readout[b * 1024 + c] += mx;
    readout[b * 1024 + 512 + c] += sm / (float)k;
}

// ---------------- final MLP + softmax ----------------
__global__ __launch_bounds__(512) void k_mlp(const float* __restrict__ readout,
                                             const float* __restrict__ W1, const float* __restrict__ b1,
                                             const float* __restrict__ W2, const float* __restrict__ b2,
                                             const float* __restrict__ W3, const float* __restrict__ b3,
                                             float* __restrict__ out) {
    int b = blockIdx.x;
    int t = threadIdx.x;
    __shared__ float r[1024];
    __shared__ float h1[512];
    __shared__ float h2[256];
    __shared__ float lg[5];
    r[t] = readout[b * 1024 + t];
    r[t + 512] = readout[b * 1024 + 512 + t];
    __syncthreads();
    float s = b1[t];
    for (int i = 0; i < 1024; ++i) s += r[i] * W1[i * 512 + t];
    h1[t] = fmaxf(s, 0.f);
    __syncthreads();
    if (t < 256) {
        float s2 = b2[t];
        for (int i = 0; i < 512; ++i) s2 += h1[i] * W2[i * 256 + t];
        h2[t] = fmaxf(s2, 0.f);
    }
    __syncthreads();
    if (t < 5) {
        float s3 = b3[t];
        for (int i = 0; i < 256; ++i) s3 += h2[i] * W3[i * 5 + t];
        lg[t] = s3;
        out[b * 5 + t] = s3;
    }
    __syncthreads();
    if (t < 5) {
        float m = lg[0];
        for (int i = 1; i < 5; ++i) m = fmaxf(m, lg[i]);
        float den = 0.f;
        for (int i = 0; i < 5; ++i) den += expf(lg[i] - m);
        out[NB * 5 + b * 5 + t] = expf(lg[t] - m) / den;
    }
}

extern "C" void kernel_launch(void* const* d_in, const int* in_sizes, int n_in,
                              void* d_out, int out_size, void* d_ws, size_t ws_size,
                              hipStream_t stream) {
    const float* x0    = (const float*)d_in[0];
    const int*   ei    = (const int*)d_in[1];
    const float* gWl   = (const float*)d_in[2];
    const float* gbl   = (const float*)d_in[3];
    const float* gWr   = (const float*)d_in[4];
    const float* gbr   = (const float*)d_in[5];
    const float* gatt  = (const float*)d_in[6];
    const float* gbias = (const float*)d_in[7];
    const float* sWrel = (const float*)d_in[8];
    const float* sbrel = (const float*)d_in[9];
    const float* sWroot= (const float*)d_in[10];
    const float* W1 = (const float*)d_in[11];
    const float* b1 = (const float*)d_in[12];
    const float* W2 = (const float*)d_in[13];
    const float* b2 = (const float*)d_in[14];
    const float* W3 = (const float*)d_in[15];
    const float* b3 = (const float*)d_in[16];
    float* out = (float*)d_out;

    char* base = (char*)d_ws;
    size_t off = 0;
    auto alloc = [&](size_t bytes) -> void* {
        void* p = base + off;
        off += (bytes + 255) & ~(size_t)255;
        return p;
    };
    int*   s_src   = (int*)alloc((size_t)ETOT * 4);
    int*   s_dst   = (int*)alloc((size_t)ETOT * 4);
    int*   s_mask  = (int*)alloc((size_t)ETOT * 4);
    int*   seid    = (int*)alloc((size_t)ETOT * 4);
    int*   rowptr  = (int*)alloc((size_t)(h_Ns[0] + 1) * 4);
    int*   cnt     = (int*)alloc((size_t)(h_Ns[0] + 1) * 4);
    float* score   = (float*)alloc((size_t)h_Ns[0] * 4);
    int*   newidx  = (int*)alloc((size_t)h_Ns[0] * 4);
    int*   sel_old = (int*)alloc((size_t)7000 * 4);
    float* sel_scale = (float*)alloc((size_t)7000 * 4);
    float* readout = (float*)alloc((size_t)NB * 1024 * 4);
    float* logitsb = (float*)alloc((size_t)(ETOT + h_Ns[0]) * 2 * 4);
    float* xlr     = (float*)alloc((size_t)h_Ns[0] * 2048 * 4);
    float* gatout  = (float*)alloc((size_t)h_Ns[0] * 512 * 4);
    float* xpool   = (float*)alloc((size_t)7000 * 512 * 4);

    hipMemsetAsync(readout, 0, (size_t)NB * 1024 * 4, stream);
    k_edge_init<<<(ETOT + 255) / 256, 256, 0, stream>>>(ei, s_src, s_dst, s_mask);

    const float* xin = x0;
    for (int i = 0; i < 4; ++i) {
        int N = h_Ns[i], ng = h_ngs[i], k = h_ks[i];
        // CSR by dst (valid edges only)
        hipMemsetAsync(cnt, 0, (size_t)(N + 1) * 4, stream);
        k_hist<<<(ETOT + 255) / 256, 256, 0, stream>>>(s_dst, s_mask, cnt);
        k_scan<<<1, 1024, 0, stream>>>(cnt, rowptr, N);
        k_scatter<<<(ETOT + 255) / 256, 256, 0, stream>>>(s_dst, s_mask, cnt, seid);
        // xl | xr GEMMs
        dim3 gg((N + 63) / 64, 16);
        k_gemm<<<gg, 256, 0, stream>>>(xin, gWl + (size_t)i * 512 * 1024, gbl + (size_t)i * 1024, xlr, N, 2048, 0);
        k_gemm<<<gg, 256, 0, stream>>>(xin, gWr + (size_t)i * 512 * 1024, gbr + (size_t)i * 1024, xlr, N, 2048, 1024);
        // attention logits (edges + self loops)
        int items = ETOT + N;
        k_logits<<<(items + 3) / 4, 256, 0, stream>>>(xlr, s_src, s_dst, s_mask, gatt + (size_t)i * 1024, logitsb, N);
        // softmax + aggregate + head-mean + bias + relu
        k_aggregate<<<N, 256, 0, stream>>>(xlr, logitsb, rowptr, seid, s_src, gbias + (size_t)i * 512, gatout, N);
        // SAG score
        k_score<<<N, 64, 0, stream>>>(gatout, rowptr, seid, s_src, sWrel + (size_t)i * 512, sWroot + (size_t)i * 512,
                                      sbrel + i, score, N);
        // top-k per graph
        k_topk<<<NB, 1024, 0, stream>>>(score, ng, k, newidx, sel_old, sel_scale);
        // pool gather
        k_pool<<<NB * k, 128, 0, stream>>>(gatout, sel_old, sel_scale, xpool);
        // edge remap
        k_remap<<<(ETOT + 255) / 256, 256, 0, stream>>>(s_src, s_dst, s_mask, newidx);
        // readout accumulate
        k_readout<<<dim3(NB, 2), 256, 0, stream>>>(xpool, k, readout);
        xin = xpool;
    }
    k_mlp<<<NB, 512, 0, stream>>>(readout, W1, b1, W2, b2, W3, b3, out);
}

// Round 2
// 1910.035 us; speedup vs baseline: 1.5666x; 1.5666x over previous
//
#include <hip/hip_runtime.h>
#include <math.h>

#define NB   4
#define NG0  2500
#define ETOT 100000
#define CH   512
#define NEGS 0.2f

// N per layer in: 10000, 7000, 4900, 3432 ; after last pool: 2404
static const int h_Ns[5]  = {10000, 7000, 4900, 3432, 2404};
static const int h_ngs[4] = {2500, 1750, 1225, 858};
static const int h_ks[4]  = {1750, 1225, 858, 601};

// ---------------- edge init ----------------
__global__ void k_edge_init(const int* __restrict__ ei, int* src, int* dst, int* mask) {
    int e = blockIdx.x * blockDim.x + threadIdx.x;
    if (e < ETOT) { src[e] = ei[e]; dst[e] = ei[ETOT + e]; mask[e] = 1; }
}

// ---------------- CSR build ----------------
__global__ void k_hist(const int* __restrict__ dst, const int* __restrict__ mask, int* cnt) {
    int e = blockIdx.x * blockDim.x + threadIdx.x;
    if (e < ETOT && mask[e]) atomicAdd(&cnt[dst[e]], 1);
}

// single block: exclusive scan of cnt[0..N) -> rowptr[0..N], cnt becomes cursor copy
__global__ __launch_bounds__(1024) void k_scan(int* cnt, int* rowptr, int N) {
    __shared__ int lds[1024];
    __shared__ int s_carry;
    int t = threadIdx.x;
    if (t == 0) s_carry = 0;
    __syncthreads();
    for (int base = 0; base < N; base += 1024) {
        int i = base + t;
        int v = (i < N) ? cnt[i] : 0;
        lds[t] = v;
        __syncthreads();
        for (int offn = 1; offn < 1024; offn <<= 1) {
            int add = (t >= offn) ? lds[t - offn] : 0;
            __syncthreads();
            lds[t] += add;
            __syncthreads();
        }
        int excl = lds[t] - v;
        if (i < N) { int r = s_carry + excl; rowptr[i] = r; cnt[i] = r; }
        __syncthreads();
        if (t == 1023) s_carry += lds[1023];
        __syncthreads();
    }
    if (t == 0) rowptr[N] = s_carry;
}

__global__ void k_scatter(const int* __restrict__ dst, const int* __restrict__ mask,
                          int* cursor, int* seid) {
    int e = blockIdx.x * blockDim.x + threadIdx.x;
    if (e < ETOT && mask[e]) { int p = atomicAdd(&cursor[dst[e]], 1); seid[p] = e; }
}

// ---------------- GEMM: out[row, ooff+col] = A[row,:512] @ W[:512, col<1024] + bias ----------------
__global__ __launch_bounds__(256) void k_gemm(const float* __restrict__ A, const float* __restrict__ W,
                                              const float* __restrict__ bias, float* __restrict__ out,
                                              int M, int ldo, int ooff) {
    __shared__ float As[64][17];
    __shared__ float Bs[16][68];
    int tid = threadIdx.x;
    int rowBase = blockIdx.x * 64;
    int colBase = blockIdx.y * 64;
    int tr = tid >> 4, tc = tid & 15;
    float acc[4][4];
#pragma unroll
    for (int a = 0; a < 4; ++a)
#pragma unroll
        for (int b = 0; b < 4; ++b) acc[a][b] = 0.f;
    int ar = tid >> 2, akc = (tid & 3) * 4;
    int br = tid >> 4, bc = (tid & 15) * 4;
    for (int k0 = 0; k0 < 512; k0 += 16) {
        int arow = rowBase + ar;
        if (arow < M) {
            const float4 v = *(const float4*)(A + (size_t)arow * 512 + k0 + akc);
            As[ar][akc] = v.x; As[ar][akc + 1] = v.y; As[ar][akc + 2] = v.z; As[ar][akc + 3] = v.w;
        } else {
            As[ar][akc] = 0.f; As[ar][akc + 1] = 0.f; As[ar][akc + 2] = 0.f; As[ar][akc + 3] = 0.f;
        }
        const float4 w = *(const float4*)(W + (size_t)(k0 + br) * 1024 + colBase + bc);
        Bs[br][bc] = w.x; Bs[br][bc + 1] = w.y; Bs[br][bc + 2] = w.z; Bs[br][bc + 3] = w.w;
        __syncthreads();
#pragma unroll
        for (int kk = 0; kk < 16; ++kk) {
            float a0 = As[tr * 4 + 0][kk], a1 = As[tr * 4 + 1][kk], a2 = As[tr * 4 + 2][kk], a3 = As[tr * 4 + 3][kk];
            float b0 = Bs[kk][tc * 4 + 0], b1v = Bs[kk][tc * 4 + 1], b2v = Bs[kk][tc * 4 + 2], b3v = Bs[kk][tc * 4 + 3];
            acc[0][0] += a0 * b0; acc[0][1] += a0 * b1v; acc[0][2] += a0 * b2v; acc[0][3] += a0 * b3v;
            acc[1][0] += a1 * b0; acc[1][1] += a1 * b1v; acc[1][2] += a1 * b2v; acc[1][3] += a1 * b3v;
            acc[2][0] += a2 * b0; acc[2][1] += a2 * b1v; acc[2][2] += a2 * b2v; acc[2][3] += a2 * b3v;
            acc[3][0] += a3 * b0; acc[3][1] += a3 * b1v; acc[3][2] += a3 * b2v; acc[3][3] += a3 * b3v;
        }
        __syncthreads();
    }
#pragma unroll
    for (int jr = 0; jr < 4; ++jr) {
        int row = rowBase + tr * 4 + jr;
        if (row < M) {
            int col = colBase + tc * 4;
            float4 r;
            r.x = acc[jr][0] + bias[col + 0];
            r.y = acc[jr][1] + bias[col + 1];
            r.z = acc[jr][2] + bias[col + 2];
            r.w = acc[jr][3] + bias[col + 3];
            *(float4*)(out + (size_t)row * ldo + ooff + col) = r;
        }
    }
}

// ---------------- edge attention logits (one wave per edge or self-loop) ----------------
__global__ __launch_bounds__(256) void k_logits(const float* __restrict__ xlr,
                                                const int* __restrict__ src, const int* __restrict__ dst,
                                                const int* __restrict__ mask,
                                                const float* __restrict__ att,
                                                float* __restrict__ logits, int N) {
    int wid = (blockIdx.x * blockDim.x + threadIdx.x) >> 6;
    int lane = threadIdx.x & 63;
    int items = ETOT + N;
    if (wid >= items) return;
    int s, d;
    if (wid < ETOT) {
        if (!mask[wid]) return;
        s = src[wid]; d = dst[wid];
    } else {
        s = d = wid - ETOT;
    }
    const float* xl = xlr + (size_t)s * 2048;
    const float* xr = xlr + (size_t)d * 2048 + 1024;
    float acc0 = 0.f, acc1 = 0.f;
    int c0 = lane * 8;
#pragma unroll
    for (int h = 0; h < 2; ++h) {
        const float* pa = xl + h * 512 + c0;
        const float* pb = xr + h * 512 + c0;
        const float* pt = att + h * 512 + c0;
        float a = 0.f;
#pragma unroll
        for (int j = 0; j < 2; ++j) {
            float4 va = *(const float4*)(pa + j * 4);
            float4 vb = *(const float4*)(pb + j * 4);
            float4 vt = *(const float4*)(pt + j * 4);
            float e0 = va.x + vb.x; e0 = e0 > 0.f ? e0 : NEGS * e0; a += e0 * vt.x;
            float e1 = va.y + vb.y; e1 = e1 > 0.f ? e1 : NEGS * e1; a += e1 * vt.y;
            float e2 = va.z + vb.z; e2 = e2 > 0.f ? e2 : NEGS * e2; a += e2 * vt.z;
            float e3 = va.w + vb.w; e3 = e3 > 0.f ? e3 : NEGS * e3; a += e3 * vt.w;
        }
        if (h == 0) acc0 = a; else acc1 = a;
    }
#pragma unroll
    for (int offn = 32; offn > 0; offn >>= 1) {
        acc0 += __shfl_xor(acc0, offn, 64);
        acc1 += __shfl_xor(acc1, offn, 64);
    }
    if (lane == 0) { logits[(size_t)wid * 2] = acc0; logits[(size_t)wid * 2 + 1] = acc1; }
}

// ---------------- per-dst softmax + weighted aggregate + head-mean + bias + relu ----------------
__global__ __launch_bounds__(256) void k_aggregate(const float* __restrict__ xlr,
                                                   const float* __restrict__ logits,
                                                   const int* __restrict__ rowptr, const int* __restrict__ seid,
                                                   const int* __restrict__ src,
                                                   const float* __restrict__ bias,
                                                   float* __restrict__ out, int N) {
    int d = blockIdx.x;
    if (d >= N) return;
    int rs = rowptr[d], re = rowptr[d + 1];
    int t = threadIdx.x;
    int selfe = ETOT + d;
    float sl0 = logits[(size_t)selfe * 2], sl1 = logits[(size_t)selfe * 2 + 1];
    float mx0 = sl0, mx1 = sl1;
    for (int e = rs; e < re; ++e) {
        int eid = seid[e];
        mx0 = fmaxf(mx0, logits[(size_t)eid * 2]);
        mx1 = fmaxf(mx1, logits[(size_t)eid * 2 + 1]);
    }
    float den0 = __expf(sl0 - mx0), den1 = __expf(sl1 - mx1);
    for (int e = rs; e < re; ++e) {
        int eid = seid[e];
        den0 += __expf(logits[(size_t)eid * 2] - mx0);
        den1 += __expf(logits[(size_t)eid * 2 + 1] - mx1);
    }
    float invd0 = 1.f / fmaxf(den0, 1e-16f);
    float invd1 = 1.f / fmaxf(den1, 1e-16f);
    int elem = t * 4;
    int h = t >> 7;
    float mxh = h ? mx1 : mx0;
    float invdh = h ? invd1 : invd0;
    float ax = 0.f, ay = 0.f, az = 0.f, aw = 0.f;
    {
        float al = __expf((h ? sl1 : sl0) - mxh) * invdh;
        float4 v = *(const float4*)(xlr + (size_t)d * 2048 + elem);
        ax += al * v.x; ay += al * v.y; az += al * v.z; aw += al * v.w;
    }
    for (int e = rs; e < re; ++e) {
        int eid = seid[e];
        int s = src[eid];
        float al = __expf(logits[(size_t)eid * 2 + h] - mxh) * invdh;
        float4 v = *(const float4*)(xlr + (size_t)s * 2048 + elem);
        ax += al * v.x; ay += al * v.y; az += al * v.z; aw += al * v.w;
    }
    __shared__ float lds[1024];
    lds[elem + 0] = ax; lds[elem + 1] = ay; lds[elem + 2] = az; lds[elem + 3] = aw;
    __syncthreads();
    if (t < 128) {
        int c = t * 4;
        float4 bb = *(const float4*)(bias + c);
        float4 r;
        r.x = fmaxf(0.5f * (lds[c + 0] + lds[512 + c + 0]) + bb.x, 0.f);
        r.y = fmaxf(0.5f * (lds[c + 1] + lds[512 + c + 1]) + bb.y, 0.f);
        r.z = fmaxf(0.5f * (lds[c + 2] + lds[512 + c + 2]) + bb.z, 0.f);
        r.w = fmaxf(0.5f * (lds[c + 3] + lds[512 + c + 3]) + bb.w, 0.f);
        *(float4*)(out + (size_t)d * 512 + c) = r;
    }
}

// ---------------- SAG score: GraphConv (agg@Wrel + brel + x@Wroot) ----------------
__global__ __launch_bounds__(64) void k_score(const float* __restrict__ x,
                                              const int* __restrict__ rowptr, const int* __restrict__ seid,
                                              const int* __restrict__ src,
                                              const float* __restrict__ Wrel, const float* __restrict__ Wroot,
                                              const float* __restrict__ brel_p,
                                              float* __restrict__ score, int N) {
    int d = blockIdx.x;
    if (d >= N) return;
    int lane = threadIdx.x;
    int c0 = lane * 8;
    float agg[8];
#pragma unroll
    for (int j = 0; j < 8; ++j) agg[j] = 0.f;
    int rs = rowptr[d], re = rowptr[d + 1];
    for (int e = rs; e < re; ++e) {
        int s = src[seid[e]];
        const float* xs = x + (size_t)s * 512 + c0;
#pragma unroll
        for (int j = 0; j < 8; ++j) agg[j] += xs[j];
    }
    const float* xd = x + (size_t)d * 512 + c0;
    float p = 0.f;
#pragma unroll
    for (int j = 0; j < 8; ++j) p += agg[j] * Wrel[c0 + j] + xd[j] * Wroot[c0 + j];
#pragma unroll
    for (int offn = 32; offn > 0; offn >>= 1) p += __shfl_xor(p, offn, 64);
    if (lane == 0) score[d] = p + brel_p[0];
}

// ---------------- per-graph top-k via bitonic sort in LDS ----------------
__global__ __launch_bounds__(1024) void k_topk(const float* __restrict__ score, int ng, int k,
                                               int* __restrict__ newidx, int* __restrict__ sel_old,
                                               float* __restrict__ sel_scale) {
    int b = blockIdx.x;
    __shared__ float v[4096];
    __shared__ int ix[4096];
    int t = threadIdx.x;
    for (int i = t; i < 4096; i += 1024) {
        if (i < ng) {
            v[i] = score[b * ng + i];
            ix[i] = i;
            newidx[b * ng + i] = -1;
        } else {
            v[i] = -INFINITY;
            ix[i] = 0x7fffffff;
        }
    }
    __syncthreads();
    for (int size = 2; size <= 4096; size <<= 1) {
        for (int stride = size >> 1; stride > 0; stride >>= 1) {
            for (int i = t; i < 4096; i += 1024) {
                int j = i ^ stride;
                if (j > i) {
                    bool desc = ((i & size) == 0);
                    float vi = v[i], vj = v[j];
                    int xi = ix[i], xj = ix[j];
                    bool sw = desc ? (vi < vj || (vi == vj && xi > xj))
                                   : (vi > vj || (vi == vj && xi < xj));
                    if (sw) { v[i] = vj; v[j] = vi; ix[i] = xj; ix[j] = xi; }
                }
            }
            __syncthreads();
        }
    }
    for (int j = t; j < k; j += 1024) {
        int oldg = b * ng + ix[j];
        int newg = b * k + j;
        newidx[oldg] = newg;
        sel_old[newg] = oldg;
        sel_scale[newg] = tanhf(v[j]);
    }
}

// ---------------- pool gather + tanh scale ----------------
__global__ __launch_bounds__(128) void k_pool(const float* __restrict__ x, const int* __restrict__ sel_old,
                                              const float* __restrict__ sel_scale, float* __restrict__ xn) {
    int nn = blockIdx.x;
    int so = sel_old[nn];
    float sc = sel_scale[nn];
    int c = threadIdx.x * 4;
    float4 vv = *(const float4*)(x + (size_t)so * 512 + c);
    vv.x *= sc; vv.y *= sc; vv.z *= sc; vv.w *= sc;
    *(float4*)(xn + (size_t)nn * 512 + c) = vv;
}

// ---------------- edge remap ----------------
__global__ void k_remap(int* src, int* dst, int* mask, const int* __restrict__ newidx) {
    int e = blockIdx.x * blockDim.x + threadIdx.x;
    if (e >= ETOT) return;
    if (!mask[e]) return;
    int ns = newidx[src[e]];
    int nd = newidx[dst[e]];
    if (ns >= 0 && nd >= 0) { src[e] = ns; dst[e] = nd; }
    else mask[e] = 0;
}

// ---------------- readout phase 1: partial max/sum over row chunks ----------------
// grid (NB, 2 colgroups, 8 rowchunks), block 256 = 64 float4-cols x 4 rowlanes
__global__ __launch_bounds__(256) void k_readout_part(const float* __restrict__ x, int k,
                                                      float* __restrict__ pmax, float* __restrict__ psum) {
    int b = blockIdx.x, cg = blockIdx.y, rc = blockIdx.z;
    int t = threadIdx.x;
    int c4 = (t & 63);               // float4 index within colgroup
    int rl = t >> 6;                 // rowlane 0..3
    int col = cg * 256 + c4 * 4;
    int rstart = rc * 4 + rl;        // global row-lane 0..31
    float4 mx = make_float4(-1e30f, -1e30f, -1e30f, -1e30f);
    float4 sm = make_float4(0.f, 0.f, 0.f, 0.f);
    for (int j = rstart; j < k; j += 32) {
        float4 v = *(const float4*)(x + ((size_t)(b * k + j)) * 512 + col);
        mx.x = fmaxf(mx.x, v.x); mx.y = fmaxf(mx.y, v.y); mx.z = fmaxf(mx.z, v.z); mx.w = fmaxf(mx.w, v.w);
        sm.x += v.x; sm.y += v.y; sm.z += v.z; sm.w += v.w;
    }
    __shared__ float lmx[256 * 4];
    __shared__ float lsm[256 * 4];
    int li = c4 * 4 + rl * 256;
    lmx[li + 0] = mx.x; lmx[li + 1] = mx.y; lmx[li + 2] = mx.z; lmx[li + 3] = mx.w;
    lsm[li + 0] = sm.x; lsm[li + 1] = sm.y; lsm[li + 2] = sm.z; lsm[li + 3] = sm.w;
    __syncthreads();
    if (rl == 0) {
        int ci = c4 * 4;
#pragma unroll
        for (int q = 0; q < 4; ++q) {
            float m = fmaxf(fmaxf(lmx[ci + q], lmx[ci + q + 256]), fmaxf(lmx[ci + q + 512], lmx[ci + q + 768]));
            float s = lsm[ci + q] + lsm[ci + q + 256] + lsm[ci + q + 512] + lsm[ci + q + 768];
            size_t o = ((size_t)(b * 8 + rc)) * 512 + col + q;
            pmax[o] = m;
            psum[o] = s;
        }
    }
}

// ---------------- readout phase 2: fold 8 chunks, accumulate ----------------
__global__ __launch_bounds__(512) void k_readout_fin(const float* __restrict__ pmax, const float* __restrict__ psum,
                                                     int k, float* __restrict__ readout) {
    int b = blockIdx.x;
    int c = threadIdx.x;
    float m = -1e30f, s = 0.f;
#pragma unroll
    for (int rc = 0; rc < 8; ++rc) {
        size_t o = ((size_t)(b * 8 + rc)) * 512 + c;
        m = fmaxf(m, pmax[o]);
        s += psum[o];
    }
    readout[b * 1024 + c] += m;
    readout[b * 1024 + 512 + c] += s / (float)k;
}

// ---------------- final MLP + softmax ----------------
__global__ __launch_bounds__(512) void k_mlp(const float* __restrict__ readout,
                                             const float* __restrict__ W1, const float* __restrict__ b1,
                                             const float* __restrict__ W2, const float* __restrict__ b2,
                                             const float* __restrict__ W3, const float* __restrict__ b3,
                                             float* __restrict__ out) {
    int b = blockIdx.x;
    int t = threadIdx.x;
    __shared__ float r[1024];
    __shared__ float h1[512];
    __shared__ float h2[256];
    __shared__ float lg[5];
    r[t] = readout[b * 1024 + t];
    r[t + 512] = readout[b * 1024 + 512 + t];
    __syncthreads();
    float s = b1[t];
    for (int i = 0; i < 1024; ++i) s += r[i] * W1[i * 512 + t];
    h1[t] = fmaxf(s, 0.f);
    __syncthreads();
    if (t < 256) {
        float s2 = b2[t];
        for (int i = 0; i < 512; ++i) s2 += h1[i] * W2[i * 256 + t];
        h2[t] = fmaxf(s2, 0.f);
    }
    __syncthreads();
    if (t < 5) {
        float s3 = b3[t];
        for (int i = 0; i < 256; ++i) s3 += h2[i] * W3[i * 5 + t];
        lg[t] = s3;
        out[b * 5 + t] = s3;
    }
    __syncthreads();
    if (t < 5) {
        float m = lg[0];
        for (int i = 1; i < 5; ++i) m = fmaxf(m, lg[i]);
        float den = 0.f;
        for (int i = 0; i < 5; ++i) den += expf(lg[i] - m);
        out[NB * 5 + b * 5 + t] = expf(lg[t] - m) / den;
    }
}

extern "C" void kernel_launch(void* const* d_in, const int* in_sizes, int n_in,
                              void* d_out, int out_size, void* d_ws, size_t ws_size,
                              hipStream_t stream) {
    const float* x0    = (const float*)d_in[0];
    const int*   ei    = (const int*)d_in[1];
    const float* gWl   = (const float*)d_in[2];
    const float* gbl   = (const float*)d_in[3];
    const float* gWr   = (const float*)d_in[4];
    const float* gbr   = (const float*)d_in[5];
    const float* gatt  = (const float*)d_in[6];
    const float* gbias = (const float*)d_in[7];
    const float* sWrel = (const float*)d_in[8];
    const float* sbrel = (const float*)d_in[9];
    const float* sWroot= (const float*)d_in[10];
    const float* W1 = (const float*)d_in[11];
    const float* b1 = (const float*)d_in[12];
    const float* W2 = (const float*)d_in[13];
    const float* b2 = (const float*)d_in[14];
    const float* W3 = (const float*)d_in[15];
    const float* b3 = (const float*)d_in[16];
    float* out = (float*)d_out;

    char* base = (char*)d_ws;
    size_t off = 0;
    auto alloc = [&](size_t bytes) -> void* {
        void* p = base + off;
        off += (bytes + 255) & ~(size_t)255;
        return p;
    };
    int*   s_src   = (int*)alloc((size_t)ETOT * 4);
    int*   s_dst   = (int*)alloc((size_t)ETOT * 4);
    int*   s_mask  = (int*)alloc((size_t)ETOT * 4);
    int*   seid    = (int*)alloc((size_t)ETOT * 4);
    int*   rowptr  = (int*)alloc((size_t)(h_Ns[0] + 1) * 4);
    int*   cnt     = (int*)alloc((size_t)(h_Ns[0] + 1) * 4);
    float* score   = (float*)alloc((size_t)h_Ns[0] * 4);
    int*   newidx  = (int*)alloc((size_t)h_Ns[0] * 4);
    int*   sel_old = (int*)alloc((size_t)7000 * 4);
    float* sel_scale = (float*)alloc((size_t)7000 * 4);
    float* readout = (float*)alloc((size_t)NB * 1024 * 4);
    float* pmax    = (float*)alloc((size_t)NB * 8 * 512 * 4);
    float* psum    = (float*)alloc((size_t)NB * 8 * 512 * 4);
    float* logitsb = (float*)alloc((size_t)(ETOT + h_Ns[0]) * 2 * 4);
    float* xlr     = (float*)alloc((size_t)h_Ns[0] * 2048 * 4);
    float* gatout  = (float*)alloc((size_t)h_Ns[0] * 512 * 4);
    float* xpool   = (float*)alloc((size_t)7000 * 512 * 4);

    hipMemsetAsync(readout, 0, (size_t)NB * 1024 * 4, stream);
    k_edge_init<<<(ETOT + 255) / 256, 256, 0, stream>>>(ei, s_src, s_dst, s_mask);

    const float* xin = x0;
    for (int i = 0; i < 4; ++i) {
        int N = h_Ns[i], ng = h_ngs[i], k = h_ks[i];
        // CSR by dst (valid edges only)
        hipMemsetAsync(cnt, 0, (size_t)(N + 1) * 4, stream);
        k_hist<<<(ETOT + 255) / 256, 256, 0, stream>>>(s_dst, s_mask, cnt);
        k_scan<<<1, 1024, 0, stream>>>(cnt, rowptr, N);
        k_scatter<<<(ETOT + 255) / 256, 256, 0, stream>>>(s_dst, s_mask, cnt, seid);
        // xl | xr GEMMs
        dim3 gg((N + 63) / 64, 16);
        k_gemm<<<gg, 256, 0, stream>>>(xin, gWl + (size_t)i * 512 * 1024, gbl + (size_t)i * 1024, xlr, N, 2048, 0);
        k_gemm<<<gg, 256, 0, stream>>>(xin, gWr + (size_t)i * 512 * 1024, gbr + (size_t)i * 1024, xlr, N, 2048, 1024);
        // attention logits (edges + self loops)
        int items = ETOT + N;
        k_logits<<<(items + 3) / 4, 256, 0, stream>>>(xlr, s_src, s_dst, s_mask, gatt + (size_t)i * 1024, logitsb, N);
        // softmax + aggregate + head-mean + bias + relu
        k_aggregate<<<N, 256, 0, stream>>>(xlr, logitsb, rowptr, seid, s_src, gbias + (size_t)i * 512, gatout, N);
        // SAG score
        k_score<<<N, 64, 0, stream>>>(gatout, rowptr, seid, s_src, sWrel + (size_t)i * 512, sWroot + (size_t)i * 512,
                                      sbrel + i, score, N);
        // top-k per graph
        k_topk<<<NB, 1024, 0, stream>>>(score, ng, k, newidx, sel_old, sel_scale);
        // pool gather
        k_pool<<<NB * k, 128, 0, stream>>>(gatout, sel_old, sel_scale, xpool);
        // edge remap
        k_remap<<<(ETOT + 255) / 256, 256, 0, stream>>>(s_src, s_dst, s_mask, newidx);
        // readout (two-phase, parallel over rows)
        k_readout_part<<<dim3(NB, 2, 8), 256, 0, stream>>>(xpool, k, pmax, psum);
        k_readout_fin<<<NB, 512, 0, stream>>>(pmax, psum, k, readout);
        xin = xpool;
    }
    k_mlp<<<NB, 512, 0, stream>>>(readout, W1, b1, W2, b2, W3, b3, out);
}

// Round 3
// 1159.943 us; speedup vs baseline: 2.5796x; 1.6467x over previous
//
#include <hip/hip_runtime.h>
#include <math.h>

#define NB   4
#define NG0  2500
#define ETOT 100000
#define CH   512
#define NEGS 0.2f

static const int h_Ns[5]  = {10000, 7000, 4900, 3432, 2404};
static const int h_ngs[4] = {2500, 1750, 1225, 858};
static const int h_ks[4]  = {1750, 1225, 858, 601};

typedef __bf16 bf16x8 __attribute__((ext_vector_type(8)));
typedef float  f32x4  __attribute__((ext_vector_type(4)));

// ---------------- edge init ----------------
__global__ void k_edge_init(const int* __restrict__ ei, int* src, int* dst, int* mask) {
    int e = blockIdx.x * blockDim.x + threadIdx.x;
    if (e < ETOT) { src[e] = ei[e]; dst[e] = ei[ETOT + e]; mask[e] = 1; }
}

// ---------------- CSR build ----------------
__global__ void k_hist(const int* __restrict__ dst, const int* __restrict__ mask, int* cnt) {
    int e = blockIdx.x * blockDim.x + threadIdx.x;
    if (e < ETOT && mask[e]) atomicAdd(&cnt[dst[e]], 1);
}

__global__ __launch_bounds__(1024) void k_scan(int* cnt, int* rowptr, int N) {
    __shared__ int lds[1024];
    __shared__ int s_carry;
    int t = threadIdx.x;
    if (t == 0) s_carry = 0;
    __syncthreads();
    for (int base = 0; base < N; base += 1024) {
        int i = base + t;
        int v = (i < N) ? cnt[i] : 0;
        lds[t] = v;
        __syncthreads();
        for (int offn = 1; offn < 1024; offn <<= 1) {
            int add = (t >= offn) ? lds[t - offn] : 0;
            __syncthreads();
            lds[t] += add;
            __syncthreads();
        }
        int excl = lds[t] - v;
        if (i < N) { int r = s_carry + excl; rowptr[i] = r; cnt[i] = r; }
        __syncthreads();
        if (t == 1023) s_carry += lds[1023];
        __syncthreads();
    }
    if (t == 0) rowptr[N] = s_carry;
}

__global__ void k_scatter(const int* __restrict__ dst, const int* __restrict__ mask,
                          int* cursor, int* seid) {
    int e = blockIdx.x * blockDim.x + threadIdx.x;
    if (e < ETOT && mask[e]) { int p = atomicAdd(&cursor[dst[e]], 1); seid[p] = e; }
}

// ---------------- f32 -> bf16 hi/lo split ----------------
__global__ void k_cvtA(const float* __restrict__ x, __bf16* __restrict__ hi,
                       __bf16* __restrict__ lo, int n) {
    int i = (blockIdx.x * blockDim.x + threadIdx.x) * 8;
    if (i >= n) return;
    float4 a = *(const float4*)(x + i);
    float4 b = *(const float4*)(x + i + 4);
    float f[8] = {a.x, a.y, a.z, a.w, b.x, b.y, b.z, b.w};
    bf16x8 vh, vl;
#pragma unroll
    for (int j = 0; j < 8; ++j) {
        __bf16 h = (__bf16)f[j];
        vh[j] = h;
        vl[j] = (__bf16)(f[j] - (float)h);
    }
    *(bf16x8*)(hi + i) = vh;
    *(bf16x8*)(lo + i) = vl;
}

// ---------------- W transpose + split: src [512][1024] -> Wt [1024][512] hi/lo ----------------
// grid (32, 16, 8): z = matrix (2*layer + {0=Wl,1=Wr}), block (32,8)
__global__ void k_cvtWt(const float* __restrict__ gWl, const float* __restrict__ gWr,
                        __bf16* __restrict__ WtH, __bf16* __restrict__ WtL) {
    int m = blockIdx.z;
    const float* src = ((m & 1) ? gWr : gWl) + (size_t)(m >> 1) * 512 * 1024;
    __bf16* oh = WtH + (size_t)m * 1024 * 512;
    __bf16* ol = WtL + (size_t)m * 1024 * 512;
    int nb = blockIdx.x * 32, kb = blockIdx.y * 32;
    __shared__ float tile[32][33];
#pragma unroll
    for (int j = 0; j < 4; ++j) {
        int kk = threadIdx.y + j * 8;
        tile[kk][threadIdx.x] = src[(size_t)(kb + kk) * 1024 + nb + threadIdx.x];
    }
    __syncthreads();
#pragma unroll
    for (int j = 0; j < 4; ++j) {
        int nn = threadIdx.y + j * 8;
        float v = tile[threadIdx.x][nn];
        __bf16 h = (__bf16)v;
        __bf16 l = (__bf16)(v - (float)h);
        oh[(size_t)(nb + nn) * 512 + kb + threadIdx.x] = h;
        ol[(size_t)(nb + nn) * 512 + kb + threadIdx.x] = l;
    }
}

// ---------------- bf16x3 MFMA GEMM: out[row, ooff+col] = A @ W + bias ----------------
// A hi/lo [M][512] bf16, Wt hi/lo [1024][512] bf16 (transposed). 128x128 tile, 4 waves.
#define LP 40  // padded k-stride (elements)
__global__ __launch_bounds__(256) void k_gemm3(const __bf16* __restrict__ Ah, const __bf16* __restrict__ Al,
                                               const __bf16* __restrict__ Bh, const __bf16* __restrict__ Bl,
                                               const float* __restrict__ bias, float* __restrict__ out,
                                               int M, int ldo, int ooff) {
    __shared__ __bf16 sAh[128 * LP];
    __shared__ __bf16 sAl[128 * LP];
    __shared__ __bf16 sBh[128 * LP];
    __shared__ __bf16 sBl[128 * LP];
    int tid = threadIdx.x;
    int rowBase = blockIdx.x * 128, colBase = blockIdx.y * 128;
    int wave = tid >> 6, lane = tid & 63;
    int wr = (wave >> 1) * 64, wc = (wave & 1) * 64;
    f32x4 acc[4][4];
#pragma unroll
    for (int a = 0; a < 4; ++a)
#pragma unroll
        for (int b = 0; b < 4; ++b) { acc[a][b][0] = 0.f; acc[a][b][1] = 0.f; acc[a][b][2] = 0.f; acc[a][b][3] = 0.f; }
    int srow = tid >> 1;            // 0..127
    int kc = (tid & 1) * 16;        // element offset within 32-k tile
    int kf = 8 * (lane >> 4);       // frag k-offset
    int fl = lane & 15;
    for (int k0 = 0; k0 < 512; k0 += 32) {
        // global loads into regs
        uint4 a0, a1, l0, l1;
        int gr = rowBase + srow;
        if (gr < M) {
            const uint4* pa = (const uint4*)(Ah + (size_t)gr * 512 + k0 + kc);
            a0 = pa[0]; a1 = pa[1];
            const uint4* pl = (const uint4*)(Al + (size_t)gr * 512 + k0 + kc);
            l0 = pl[0]; l1 = pl[1];
        } else {
            a0 = make_uint4(0, 0, 0, 0); a1 = a0; l0 = a0; l1 = a0;
        }
        int gn = colBase + srow;
        const uint4* pb = (const uint4*)(Bh + (size_t)gn * 512 + k0 + kc);
        uint4 b0 = pb[0], b1 = pb[1];
        const uint4* pbl = (const uint4*)(Bl + (size_t)gn * 512 + k0 + kc);
        uint4 bl0 = pbl[0], bl1 = pbl[1];
        __syncthreads();
        *(uint4*)&sAh[srow * LP + kc] = a0; *(uint4*)&sAh[srow * LP + kc + 8] = a1;
        *(uint4*)&sAl[srow * LP + kc] = l0; *(uint4*)&sAl[srow * LP + kc + 8] = l1;
        *(uint4*)&sBh[srow * LP + kc] = b0; *(uint4*)&sBh[srow * LP + kc + 8] = b1;
        *(uint4*)&sBl[srow * LP + kc] = bl0; *(uint4*)&sBl[srow * LP + kc + 8] = bl1;
        __syncthreads();
        bf16x8 afh[4], afl[4], bfh[4], bfl[4];
#pragma unroll
        for (int fr = 0; fr < 4; ++fr) {
            int r = wr + fr * 16 + fl;
            afh[fr] = *(const bf16x8*)&sAh[r * LP + kf];
            afl[fr] = *(const bf16x8*)&sAl[r * LP + kf];
        }
#pragma unroll
        for (int fc = 0; fc < 4; ++fc) {
            int c = wc + fc * 16 + fl;
            bfh[fc] = *(const bf16x8*)&sBh[c * LP + kf];
            bfl[fc] = *(const bf16x8*)&sBl[c * LP + kf];
        }
#pragma unroll
        for (int fr = 0; fr < 4; ++fr) {
#pragma unroll
            for (int fc = 0; fc < 4; ++fc) {
                acc[fr][fc] = __builtin_amdgcn_mfma_f32_16x16x32_bf16(afh[fr], bfh[fc], acc[fr][fc], 0, 0, 0);
                acc[fr][fc] = __builtin_amdgcn_mfma_f32_16x16x32_bf16(afh[fr], bfl[fc], acc[fr][fc], 0, 0, 0);
                acc[fr][fc] = __builtin_amdgcn_mfma_f32_16x16x32_bf16(afl[fr], bfh[fc], acc[fr][fc], 0, 0, 0);
            }
        }
    }
    int orow0 = rowBase + wr + 4 * (lane >> 4);
    int ocol0 = colBase + wc + fl;
#pragma unroll
    for (int fr = 0; fr < 4; ++fr) {
#pragma unroll
        for (int fc = 0; fc < 4; ++fc) {
            int col = ocol0 + fc * 16;
            float bv = bias[col];
#pragma unroll
            for (int j = 0; j < 4; ++j) {
                int row = orow0 + fr * 16 + j;
                if (row < M) out[(size_t)row * ldo + ooff + col] = acc[fr][fc][j] + bv;
            }
        }
    }
}

// ---------------- edge attention logits (one wave per edge or self-loop) ----------------
__global__ __launch_bounds__(256) void k_logits(const float* __restrict__ xlr,
                                                const int* __restrict__ src, const int* __restrict__ dst,
                                                const int* __restrict__ mask,
                                                const float* __restrict__ att,
                                                float* __restrict__ logits, int N) {
    int wid = (blockIdx.x * blockDim.x + threadIdx.x) >> 6;
    int lane = threadIdx.x & 63;
    int items = ETOT + N;
    if (wid >= items) return;
    int s, d;
    if (wid < ETOT) {
        if (!mask[wid]) return;
        s = src[wid]; d = dst[wid];
    } else {
        s = d = wid - ETOT;
    }
    const float* xl = xlr + (size_t)s * 2048;
    const float* xr = xlr + (size_t)d * 2048 + 1024;
    float acc0 = 0.f, acc1 = 0.f;
    int c0 = lane * 8;
#pragma unroll
    for (int h = 0; h < 2; ++h) {
        const float* pa = xl + h * 512 + c0;
        const float* pb = xr + h * 512 + c0;
        const float* pt = att + h * 512 + c0;
        float a = 0.f;
#pragma unroll
        for (int j = 0; j < 2; ++j) {
            float4 va = *(const float4*)(pa + j * 4);
            float4 vb = *(const float4*)(pb + j * 4);
            float4 vt = *(const float4*)(pt + j * 4);
            float e0 = va.x + vb.x; e0 = e0 > 0.f ? e0 : NEGS * e0; a += e0 * vt.x;
            float e1 = va.y + vb.y; e1 = e1 > 0.f ? e1 : NEGS * e1; a += e1 * vt.y;
            float e2 = va.z + vb.z; e2 = e2 > 0.f ? e2 : NEGS * e2; a += e2 * vt.z;
            float e3 = va.w + vb.w; e3 = e3 > 0.f ? e3 : NEGS * e3; a += e3 * vt.w;
        }
        if (h == 0) acc0 = a; else acc1 = a;
    }
#pragma unroll
    for (int offn = 32; offn > 0; offn >>= 1) {
        acc0 += __shfl_xor(acc0, offn, 64);
        acc1 += __shfl_xor(acc1, offn, 64);
    }
    if (lane == 0) { logits[(size_t)wid * 2] = acc0; logits[(size_t)wid * 2 + 1] = acc1; }
}

// ---------------- per-dst softmax prep: max + inv-denominator (wave per node) ----------------
__global__ __launch_bounds__(256) void k_smprep(const float* __restrict__ logits,
                                                const int* __restrict__ rowptr, const int* __restrict__ seid,
                                                float4* __restrict__ prep, int N) {
    int d = (blockIdx.x * blockDim.x + threadIdx.x) >> 6;
    int lane = threadIdx.x & 63;
    if (d >= N) return;
    int rs = rowptr[d], re = rowptr[d + 1];
    float m0 = -1e30f, m1 = -1e30f;
    for (int e = rs + lane; e < re; e += 64) {
        int eid = seid[e];
        m0 = fmaxf(m0, logits[(size_t)eid * 2]);
        m1 = fmaxf(m1, logits[(size_t)eid * 2 + 1]);
    }
#pragma unroll
    for (int o = 32; o > 0; o >>= 1) {
        m0 = fmaxf(m0, __shfl_xor(m0, o, 64));
        m1 = fmaxf(m1, __shfl_xor(m1, o, 64));
    }
    float sl0 = logits[(size_t)(ETOT + d) * 2], sl1 = logits[(size_t)(ETOT + d) * 2 + 1];
    m0 = fmaxf(m0, sl0); m1 = fmaxf(m1, sl1);
    float d0 = 0.f, d1 = 0.f;
    for (int e = rs + lane; e < re; e += 64) {
        int eid = seid[e];
        d0 += __expf(logits[(size_t)eid * 2] - m0);
        d1 += __expf(logits[(size_t)eid * 2 + 1] - m1);
    }
#pragma unroll
    for (int o = 32; o > 0; o >>= 1) {
        d0 += __shfl_xor(d0, o, 64);
        d1 += __shfl_xor(d1, o, 64);
    }
    if (lane == 0) {
        d0 += __expf(sl0 - m0);
        d1 += __expf(sl1 - m1);
        float4 p;
        p.x = m0; p.y = m1;
        p.z = 1.f / fmaxf(d0, 1e-16f);
        p.w = 1.f / fmaxf(d1, 1e-16f);
        prep[d] = p;
    }
}

// ---------------- per-edge alpha ----------------
__global__ void k_alpha(const float* __restrict__ logits, const int* __restrict__ dst,
                        const int* __restrict__ mask, const float4* __restrict__ prep,
                        float* __restrict__ alpha, int N) {
    int e = blockIdx.x * blockDim.x + threadIdx.x;
    int items = ETOT + N;
    if (e >= items) return;
    int d;
    if (e < ETOT) { if (!mask[e]) return; d = dst[e]; }
    else d = e - ETOT;
    float4 p = prep[d];
    alpha[(size_t)e * 2]     = __expf(logits[(size_t)e * 2]     - p.x) * p.z;
    alpha[(size_t)e * 2 + 1] = __expf(logits[(size_t)e * 2 + 1] - p.y) * p.w;
}

// ---------------- aggregate: sum alpha * xl[s], head-mean + bias + relu ----------------
__global__ __launch_bounds__(256) void k_aggregate(const float* __restrict__ xlr,
                                                   const float* __restrict__ alpha,
                                                   const int* __restrict__ rowptr, const int* __restrict__ seid,
                                                   const int* __restrict__ src,
                                                   const float* __restrict__ bias,
                                                   float* __restrict__ out, int N) {
    int d = blockIdx.x;
    if (d >= N) return;
    int rs = rowptr[d], re = rowptr[d + 1];
    int t = threadIdx.x;
    int elem = t * 4;
    int h = t >> 7;
    float ax = 0.f, ay = 0.f, az = 0.f, aw = 0.f;
    {
        float al = alpha[(size_t)(ETOT + d) * 2 + h];
        float4 v = *(const float4*)(xlr + (size_t)d * 2048 + elem);
        ax += al * v.x; ay += al * v.y; az += al * v.z; aw += al * v.w;
    }
    for (int e = rs; e < re; ++e) {
        int eid = seid[e];
        int s = src[eid];
        float al = alpha[(size_t)eid * 2 + h];
        float4 v = *(const float4*)(xlr + (size_t)s * 2048 + elem);
        ax += al * v.x; ay += al * v.y; az += al * v.z; aw += al * v.w;
    }
    __shared__ float lds[1024];
    lds[elem + 0] = ax; lds[elem + 1] = ay; lds[elem + 2] = az; lds[elem + 3] = aw;
    __syncthreads();
    if (t < 128) {
        int c = t * 4;
        float4 bb = *(const float4*)(bias + c);
        float4 r;
        r.x = fmaxf(0.5f * (lds[c + 0] + lds[512 + c + 0]) + bb.x, 0.f);
        r.y = fmaxf(0.5f * (lds[c + 1] + lds[512 + c + 1]) + bb.y, 0.f);
        r.z = fmaxf(0.5f * (lds[c + 2] + lds[512 + c + 2]) + bb.z, 0.f);
        r.w = fmaxf(0.5f * (lds[c + 3] + lds[512 + c + 3]) + bb.w, 0.f);
        *(float4*)(out + (size_t)d * 512 + c) = r;
    }
}

// ---------------- row dots: y0 = x . Wrel, y1 = x . Wroot (wave per node) ----------------
__global__ __launch_bounds__(256) void k_rowdots(const float* __restrict__ x,
                                                 const float* __restrict__ Wrel, const float* __restrict__ Wroot,
                                                 float* __restrict__ y0, float* __restrict__ y1, int N) {
    int d = (blockIdx.x * blockDim.x + threadIdx.x) >> 6;
    int lane = threadIdx.x & 63;
    if (d >= N) return;
    const float* xd = x + (size_t)d * 512 + lane * 8;
    const float* wr = Wrel + lane * 8;
    const float* wo = Wroot + lane * 8;
    float s0 = 0.f, s1 = 0.f;
#pragma unroll
    for (int j = 0; j < 2; ++j) {
        float4 v = *(const float4*)(xd + j * 4);
        float4 a = *(const float4*)(wr + j * 4);
        float4 b = *(const float4*)(wo + j * 4);
        s0 += v.x * a.x + v.y * a.y + v.z * a.z + v.w * a.w;
        s1 += v.x * b.x + v.y * b.y + v.z * b.z + v.w * b.w;
    }
#pragma unroll
    for (int o = 32; o > 0; o >>= 1) {
        s0 += __shfl_xor(s0, o, 64);
        s1 += __shfl_xor(s1, o, 64);
    }
    if (lane == 0) { y0[d] = s0; y1[d] = s1; }
}

// ---------------- score via CSR scalar sums ----------------
__global__ void k_score2(const float* __restrict__ y0, const float* __restrict__ y1,
                         const int* __restrict__ rowptr, const int* __restrict__ seid,
                         const int* __restrict__ src, const float* __restrict__ brel_p,
                         float* __restrict__ score, int N) {
    int d = blockIdx.x * blockDim.x + threadIdx.x;
    if (d >= N) return;
    float s = y1[d] + brel_p[0];
    int rs = rowptr[d], re = rowptr[d + 1];
    for (int e = rs; e < re; ++e) s += y0[src[seid[e]]];
    score[d] = s;
}

// ---------------- per-graph top-k via radix select (block per graph) ----------------
__global__ __launch_bounds__(256) void k_topk_radix(const float* __restrict__ score, int ng, int k,
                                                    int* __restrict__ newidx, int* __restrict__ sel_old,
                                                    float* __restrict__ sel_scale) {
    int b = blockIdx.x;
    int t = threadIdx.x;
    __shared__ unsigned int keys[NG0];
    __shared__ int hist[256];
    __shared__ int scnt[256];
    __shared__ unsigned int s_pref, s_amask;
    __shared__ int s_krem, s_gt;
    for (int i = t; i < ng; i += 256) {
        float f = score[b * ng + i];
        unsigned int u = __float_as_uint(f);
        u = (u & 0x80000000u) ? ~u : (u | 0x80000000u);   // ascending-order map
        keys[i] = u;
        newidx[b * ng + i] = -1;
    }
    if (t == 0) { s_pref = 0u; s_amask = 0u; s_krem = k; s_gt = 0; }
    __syncthreads();
    for (int pass = 0; pass < 4; ++pass) {
        int shift = 24 - 8 * pass;
        hist[t] = 0;
        __syncthreads();
        unsigned int amask = s_amask, pref = s_pref;
        for (int i = t; i < ng; i += 256) {
            unsigned int u = keys[i];
            if ((u & amask) == pref) atomicAdd(&hist[(u >> shift) & 255], 1);
        }
        __syncthreads();
        if (t == 0) {
            int krem = s_krem, cum = 0, dsel = 0;
            for (int dd = 255; dd >= 0; --dd) {
                cum += hist[dd];
                if (cum >= krem) { dsel = dd; krem -= (cum - hist[dd]); break; }
            }
            s_pref = s_pref | ((unsigned int)dsel << shift);
            s_amask = s_amask | (0xFFu << shift);
            s_krem = krem;
        }
        __syncthreads();
    }
    unsigned int T = s_pref;
    int krem = s_krem;         // # of ==T to take (in index order)
    // stable rank among ==T: contiguous chunks
    int chunk = (ng + 255) / 256;
    int lo = t * chunk, hi = min(ng, lo + chunk);
    int ceq = 0;
    for (int i = lo; i < hi; ++i) if (keys[i] == T) ceq++;
    scnt[t] = ceq;
    __syncthreads();
    for (int o = 1; o < 256; o <<= 1) {
        int add = (t >= o) ? scnt[t - o] : 0;
        __syncthreads();
        scnt[t] += add;
        __syncthreads();
    }
    int eq_rank = scnt[t] - ceq;
    for (int i = lo; i < hi; ++i) {
        unsigned int u = keys[i];
        int slot = -1;
        if (u > T) slot = atomicAdd(&s_gt, 1);
        else if (u == T) {
            if (eq_rank < krem) slot = (k - krem) + eq_rank;
            eq_rank++;
        }
        if (slot >= 0) {
            int oldg = b * ng + i;
            int newg = b * k + slot;
            newidx[oldg] = newg;
            sel_old[newg] = oldg;
            sel_scale[newg] = tanhf(score[oldg]);
        }
    }
}

// ---------------- pool gather + tanh scale ----------------
__global__ __launch_bounds__(128) void k_pool(const float* __restrict__ x, const int* __restrict__ sel_old,
                                              const float* __restrict__ sel_scale, float* __restrict__ xn) {
    int nn = blockIdx.x;
    int so = sel_old[nn];
    float sc = sel_scale[nn];
    int c = threadIdx.x * 4;
    float4 vv = *(const float4*)(x + (size_t)so * 512 + c);
    vv.x *= sc; vv.y *= sc; vv.z *= sc; vv.w *= sc;
    *(float4*)(xn + (size_t)nn * 512 + c) = vv;
}

// ---------------- edge remap ----------------
__global__ void k_remap(int* src, int* dst, int* mask, const int* __restrict__ newidx) {
    int e = blockIdx.x * blockDim.x + threadIdx.x;
    if (e >= ETOT) return;
    if (!mask[e]) return;
    int ns = newidx[src[e]];
    int nd = newidx[dst[e]];
    if (ns >= 0 && nd >= 0) { src[e] = ns; dst[e] = nd; }
    else mask[e] = 0;
}

// ---------------- readout phase 1 ----------------
__global__ __launch_bounds__(256) void k_readout_part(const float* __restrict__ x, int k,
                                                      float* __restrict__ pmax, float* __restrict__ psum) {
    int b = blockIdx.x, cg = blockIdx.y, rc = blockIdx.z;
    int t = threadIdx.x;
    int c4 = (t & 63);
    int rl = t >> 6;
    int col = cg * 256 + c4 * 4;
    int rstart = rc * 4 + rl;
    float4 mx = make_float4(-1e30f, -1e30f, -1e30f, -1e30f);
    float4 sm = make_float4(0.f, 0.f, 0.f, 0.f);
    for (int j = rstart; j < k; j += 32) {
        float4 v = *(const float4*)(x + ((size_t)(b * k + j)) * 512 + col);
        mx.x = fmaxf(mx.x, v.x); mx.y = fmaxf(mx.y, v.y); mx.z = fmaxf(mx.z, v.z); mx.w = fmaxf(mx.w, v.w);
        sm.x += v.x; sm.y += v.y; sm.z += v.z; sm.w += v.w;
    }
    __shared__ float lmx[256 * 4];
    __shared__ float lsm[256 * 4];
    int li = c4 * 4 + rl * 256;
    lmx[li + 0] = mx.x; lmx[li + 1] = mx.y; lmx[li + 2] = mx.z; lmx[li + 3] = mx.w;
    lsm[li + 0] = sm.x; lsm[li + 1] = sm.y; lsm[li + 2] = sm.z; lsm[li + 3] = sm.w;
    __syncthreads();
    if (rl == 0) {
        int ci = c4 * 4;
#pragma unroll
        for (int q = 0; q < 4; ++q) {
            float m = fmaxf(fmaxf(lmx[ci + q], lmx[ci + q + 256]), fmaxf(lmx[ci + q + 512], lmx[ci + q + 768]));
            float s = lsm[ci + q] + lsm[ci + q + 256] + lsm[ci + q + 512] + lsm[ci + q + 768];
            size_t o = ((size_t)(b * 8 + rc)) * 512 + col + q;
            pmax[o] = m;
            psum[o] = s;
        }
    }
}

// ---------------- readout phase 2 ----------------
__global__ __launch_bounds__(512) void k_readout_fin(const float* __restrict__ pmax, const float* __restrict__ psum,
                                                     int k, float* __restrict__ readout) {
    int b = blockIdx.x;
    int c = threadIdx.x;
    float m = -1e30f, s = 0.f;
#pragma unroll
    for (int rc = 0; rc < 8; ++rc) {
        size_t o = ((size_t)(b * 8 + rc)) * 512 + c;
        m = fmaxf(m, pmax[o]);
        s += psum[o];
    }
    readout[b * 1024 + c] += m;
    readout[b * 1024 + 512 + c] += s / (float)k;
}

// ---------------- final MLP + softmax ----------------
__global__ __launch_bounds__(512) void k_mlp(const float* __restrict__ readout,
                                             const float* __restrict__ W1, const float* __restrict__ b1,
                                             const float* __restrict__ W2, const float* __restrict__ b2,
                                             const float* __restrict__ W3, const float* __restrict__ b3,
                                             float* __restrict__ out) {
    int b = blockIdx.x;
    int t = threadIdx.x;
    __shared__ float r[1024];
    __shared__ float h1[512];
    __shared__ float h2[256];
    __shared__ float lg[5];
    r[t] = readout[b * 1024 + t];
    r[t + 512] = readout[b * 1024 + 512 + t];
    __syncthreads();
    float s = b1[t];
    for (int i = 0; i < 1024; ++i) s += r[i] * W1[i * 512 + t];
    h1[t] = fmaxf(s, 0.f);
    __syncthreads();
    if (t < 256) {
        float s2 = b2[t];
        for (int i = 0; i < 512; ++i) s2 += h1[i] * W2[i * 256 + t];
        h2[t] = fmaxf(s2, 0.f);
    }
    __syncthreads();
    if (t < 5) {
        float s3 = b3[t];
        for (int i = 0; i < 256; ++i) s3 += h2[i] * W3[i * 5 + t];
        lg[t] = s3;
        out[b * 5 + t] = s3;
    }
    __syncthreads();
    if (t < 5) {
        float m = lg[0];
        for (int i = 1; i < 5; ++i) m = fmaxf(m, lg[i]);
        float den = 0.f;
        for (int i = 0; i < 5; ++i) den += expf(lg[i] - m);
        out[NB * 5 + b * 5 + t] = expf(lg[t] - m) / den;
    }
}

extern "C" void kernel_launch(void* const* d_in, const int* in_sizes, int n_in,
                              void* d_out, int out_size, void* d_ws, size_t ws_size,
                              hipStream_t stream) {
    const float* x0    = (const float*)d_in[0];
    const int*   ei    = (const int*)d_in[1];
    const float* gWl   = (const float*)d_in[2];
    const float* gbl   = (const float*)d_in[3];
    const float* gWr   = (const float*)d_in[4];
    const float* gbr   = (const float*)d_in[5];
    const float* gatt  = (const float*)d_in[6];
    const float* gbias = (const float*)d_in[7];
    const float* sWrel = (const float*)d_in[8];
    const float* sbrel = (const float*)d_in[9];
    const float* sWroot= (const float*)d_in[10];
    const float* W1 = (const float*)d_in[11];
    const float* b1 = (const float*)d_in[12];
    const float* W2 = (const float*)d_in[13];
    const float* b2 = (const float*)d_in[14];
    const float* W3 = (const float*)d_in[15];
    const float* b3 = (const float*)d_in[16];
    float* out = (float*)d_out;

    char* base = (char*)d_ws;
    size_t off = 0;
    auto alloc = [&](size_t bytes) -> void* {
        void* p = base + off;
        off += (bytes + 255) & ~(size_t)255;
        return p;
    };
    int*   s_src   = (int*)alloc((size_t)ETOT * 4);
    int*   s_dst   = (int*)alloc((size_t)ETOT * 4);
    int*   s_mask  = (int*)alloc((size_t)ETOT * 4);
    int*   seid    = (int*)alloc((size_t)ETOT * 4);
    int*   rowptr  = (int*)alloc((size_t)(h_Ns[0] + 1) * 4);
    int*   cnt     = (int*)alloc((size_t)(h_Ns[0] + 1) * 4);
    float* score   = (float*)alloc((size_t)h_Ns[0] * 4);
    int*   newidx  = (int*)alloc((size_t)h_Ns[0] * 4);
    int*   sel_old = (int*)alloc((size_t)7000 * 4);
    float* sel_scale = (float*)alloc((size_t)7000 * 4);
    float* readout = (float*)alloc((size_t)NB * 1024 * 4);
    float* pmax    = (float*)alloc((size_t)NB * 8 * 512 * 4);
    float* psum    = (float*)alloc((size_t)NB * 8 * 512 * 4);
    float* logitsb = (float*)alloc((size_t)(ETOT + h_Ns[0]) * 2 * 4);
    float* alphab  = (float*)alloc((size_t)(ETOT + h_Ns[0]) * 2 * 4);
    float4* prep   = (float4*)alloc((size_t)h_Ns[0] * 16);
    float* y0      = (float*)alloc((size_t)h_Ns[0] * 4);
    float* y1      = (float*)alloc((size_t)h_Ns[0] * 4);
    float* xlr     = (float*)alloc((size_t)h_Ns[0] * 2048 * 4);
    float* gatout  = (float*)alloc((size_t)h_Ns[0] * 512 * 4);
    float* xpool   = (float*)alloc((size_t)7000 * 512 * 4);
    __bf16* Ah     = (__bf16*)alloc((size_t)h_Ns[0] * 512 * 2);
    __bf16* Al     = (__bf16*)alloc((size_t)h_Ns[0] * 512 * 2);
    __bf16* WtH    = (__bf16*)alloc((size_t)8 * 1024 * 512 * 2);
    __bf16* WtL    = (__bf16*)alloc((size_t)8 * 1024 * 512 * 2);

    hipMemsetAsync(readout, 0, (size_t)NB * 1024 * 4, stream);
    k_edge_init<<<(ETOT + 255) / 256, 256, 0, stream>>>(ei, s_src, s_dst, s_mask);
    k_cvtWt<<<dim3(32, 16, 8), dim3(32, 8), 0, stream>>>(gWl, gWr, WtH, WtL);

    const float* xin = x0;
    for (int i = 0; i < 4; ++i) {
        int N = h_Ns[i], ng = h_ngs[i], k = h_ks[i];
        // CSR by dst
        hipMemsetAsync(cnt, 0, (size_t)(N + 1) * 4, stream);
        k_hist<<<(ETOT + 255) / 256, 256, 0, stream>>>(s_dst, s_mask, cnt);
        k_scan<<<1, 1024, 0, stream>>>(cnt, rowptr, N);
        k_scatter<<<(ETOT + 255) / 256, 256, 0, stream>>>(s_dst, s_mask, cnt, seid);
        // A split
        int nA = N * 512;
        k_cvtA<<<(nA / 8 + 255) / 256, 256, 0, stream>>>(xin, Ah, Al, nA);
        // xl | xr GEMMs (bf16x3 MFMA)
        dim3 gg((N + 127) / 128, 8);
        k_gemm3<<<gg, 256, 0, stream>>>(Ah, Al, WtH + (size_t)(2 * i) * 1024 * 512, WtL + (size_t)(2 * i) * 1024 * 512,
                                        gbl + (size_t)i * 1024, xlr, N, 2048, 0);
        k_gemm3<<<gg, 256, 0, stream>>>(Ah, Al, WtH + (size_t)(2 * i + 1) * 1024 * 512, WtL + (size_t)(2 * i + 1) * 1024 * 512,
                                        gbr + (size_t)i * 1024, xlr, N, 2048, 1024);
        // attention logits
        int items = ETOT + N;
        k_logits<<<(items + 3) / 4, 256, 0, stream>>>(xlr, s_src, s_dst, s_mask, gatt + (size_t)i * 1024, logitsb, N);
        // softmax prep + alpha
        k_smprep<<<(N + 3) / 4, 256, 0, stream>>>(logitsb, rowptr, seid, prep, N);
        k_alpha<<<(items + 255) / 256, 256, 0, stream>>>(logitsb, s_dst, s_mask, prep, alphab, N);
        // aggregate
        k_aggregate<<<N, 256, 0, stream>>>(xlr, alphab, rowptr, seid, s_src, gbias + (size_t)i * 512, gatout, N);
        // SAG score via row dots
        k_rowdots<<<(N + 3) / 4, 256, 0, stream>>>(gatout, sWrel + (size_t)i * 512, sWroot + (size_t)i * 512, y0, y1, N);
        k_score2<<<(N + 255) / 256, 256, 0, stream>>>(y0, y1, rowptr, seid, s_src, sbrel + i, score, N);
        // top-k per graph (radix select)
        k_topk_radix<<<NB, 256, 0, stream>>>(score, ng, k, newidx, sel_old, sel_scale);
        // pool gather
        k_pool<<<NB * k, 128, 0, stream>>>(gatout, sel_old, sel_scale, xpool);
        // edge remap
        k_remap<<<(ETOT + 255) / 256, 256, 0, stream>>>(s_src, s_dst, s_mask, newidx);
        // readout
        k_readout_part<<<dim3(NB, 2, 8), 256, 0, stream>>>(xpool, k, pmax, psum);
        k_readout_fin<<<NB, 512, 0, stream>>>(pmax, psum, k, readout);
        xin = xpool;
    }
    k_mlp<<<NB, 512, 0, stream>>>(readout, W1, b1, W2, b2, W3, b3, out);
}

// Round 4
// 902.480 us; speedup vs baseline: 3.3155x; 1.2853x over previous
//
#include <hip/hip_runtime.h>
#include <math.h>

#define NB   4
#define NG0  2500
#define ETOT 100000
#define CH   512
#define NEGS 0.2f

static const int h_Ns[5]  = {10000, 7000, 4900, 3432, 2404};
static const int h_ngs[4] = {2500, 1750, 1225, 858};
static const int h_ks[4]  = {1750, 1225, 858, 601};

typedef __bf16 bf16x8 __attribute__((ext_vector_type(8)));
typedef __bf16 bf16x4 __attribute__((ext_vector_type(4)));
typedef float  f32x4  __attribute__((ext_vector_type(4)));

// ---------------- edge init ----------------
__global__ void k_edge_init(const int* __restrict__ ei, int* src, int* dst, int* mask) {
    int e = blockIdx.x * blockDim.x + threadIdx.x;
    if (e < ETOT) { src[e] = ei[e]; dst[e] = ei[ETOT + e]; mask[e] = 1; }
}

// ---------------- CSR build ----------------
__global__ void k_hist(const int* __restrict__ dst, const int* __restrict__ mask, int* cnt) {
    int e = blockIdx.x * blockDim.x + threadIdx.x;
    if (e < ETOT && mask[e]) atomicAdd(&cnt[dst[e]], 1);
}

// wave-shuffle hierarchical scan, single block
__global__ __launch_bounds__(1024) void k_scan(int* cnt, int* rowptr, int N) {
    __shared__ int wsum[16];
    __shared__ int s_carry;
    int t = threadIdx.x, lane = t & 63, wave = t >> 6;
    if (t == 0) s_carry = 0;
    __syncthreads();
    for (int base = 0; base < N; base += 1024) {
        int i = base + t;
        int v = (i < N) ? cnt[i] : 0;
        int x = v;
#pragma unroll
        for (int o = 1; o < 64; o <<= 1) {
            int y = __shfl_up(x, o, 64);
            if (lane >= o) x += y;
        }
        if (lane == 63) wsum[wave] = x;
        __syncthreads();
        if (wave == 0) {
            int w = (lane < 16) ? wsum[lane] : 0;
#pragma unroll
            for (int o = 1; o < 16; o <<= 1) {
                int y = __shfl_up(w, o, 64);
                if (lane >= o) w += y;
            }
            if (lane < 16) wsum[lane] = w;
        }
        __syncthreads();
        int woff = wave ? wsum[wave - 1] : 0;
        int rc = s_carry;
        int excl = woff + x - v;
        if (i < N) { int r = rc + excl; rowptr[i] = r; cnt[i] = r; }
        __syncthreads();
        if (t == 0) s_carry = rc + wsum[15];
        __syncthreads();
    }
    if (threadIdx.x == 0) rowptr[N] = s_carry;
}

// scatter src node id directly into CSR slots
__global__ void k_scatter(const int* __restrict__ dst, const int* __restrict__ src,
                          const int* __restrict__ mask, int* cursor, int* csr_src) {
    int e = blockIdx.x * blockDim.x + threadIdx.x;
    if (e < ETOT && mask[e]) { int p = atomicAdd(&cursor[dst[e]], 1); csr_src[p] = src[e]; }
}

// ---------------- f32 -> bf16 hi/lo split (layer 0 only) ----------------
__global__ void k_cvtA(const float* __restrict__ x, __bf16* __restrict__ hi,
                       __bf16* __restrict__ lo, int n) {
    int i = (blockIdx.x * blockDim.x + threadIdx.x) * 8;
    if (i >= n) return;
    float4 a = *(const float4*)(x + i);
    float4 b = *(const float4*)(x + i + 4);
    float f[8] = {a.x, a.y, a.z, a.w, b.x, b.y, b.z, b.w};
    bf16x8 vh, vl;
#pragma unroll
    for (int j = 0; j < 8; ++j) {
        __bf16 h = (__bf16)f[j];
        vh[j] = h;
        vl[j] = (__bf16)(f[j] - (float)h);
    }
    *(bf16x8*)(hi + i) = vh;
    *(bf16x8*)(lo + i) = vl;
}

// ---------------- W transpose + split: src [512][1024] -> Wt [1024][512] hi/lo ----------------
__global__ void k_cvtWt(const float* __restrict__ gWl, const float* __restrict__ gWr,
                        __bf16* __restrict__ WtH, __bf16* __restrict__ WtL) {
    int m = blockIdx.z;
    const float* src = ((m & 1) ? gWr : gWl) + (size_t)(m >> 1) * 512 * 1024;
    __bf16* oh = WtH + (size_t)m * 1024 * 512;
    __bf16* ol = WtL + (size_t)m * 1024 * 512;
    int nb = blockIdx.x * 32, kb = blockIdx.y * 32;
    __shared__ float tile[32][33];
#pragma unroll
    for (int j = 0; j < 4; ++j) {
        int kk = threadIdx.y + j * 8;
        tile[kk][threadIdx.x] = src[(size_t)(kb + kk) * 1024 + nb + threadIdx.x];
    }
    __syncthreads();
#pragma unroll
    for (int j = 0; j < 4; ++j) {
        int nn = threadIdx.y + j * 8;
        float v = tile[threadIdx.x][nn];
        __bf16 h = (__bf16)v;
        __bf16 l = (__bf16)(v - (float)h);
        oh[(size_t)(nb + nn) * 512 + kb + threadIdx.x] = h;
        ol[(size_t)(nb + nn) * 512 + kb + threadIdx.x] = l;
    }
}

// ---------------- bf16x3 MFMA GEMM ----------------
#define LP 40
__global__ __launch_bounds__(256) void k_gemm3(const __bf16* __restrict__ Ah, const __bf16* __restrict__ Al,
                                               const __bf16* __restrict__ Bh, const __bf16* __restrict__ Bl,
                                               const float* __restrict__ bias, float* __restrict__ out,
                                               int M, int ldo, int ooff) {
    __shared__ __bf16 sAh[128 * LP];
    __shared__ __bf16 sAl[128 * LP];
    __shared__ __bf16 sBh[128 * LP];
    __shared__ __bf16 sBl[128 * LP];
    int tid = threadIdx.x;
    int rowBase = blockIdx.x * 128, colBase = blockIdx.y * 128;
    int wave = tid >> 6, lane = tid & 63;
    int wr = (wave >> 1) * 64, wc = (wave & 1) * 64;
    f32x4 acc[4][4];
#pragma unroll
    for (int a = 0; a < 4; ++a)
#pragma unroll
        for (int b = 0; b < 4; ++b) { acc[a][b][0] = 0.f; acc[a][b][1] = 0.f; acc[a][b][2] = 0.f; acc[a][b][3] = 0.f; }
    int srow = tid >> 1;
    int kc = (tid & 1) * 16;
    int kf = 8 * (lane >> 4);
    int fl = lane & 15;
    for (int k0 = 0; k0 < 512; k0 += 32) {
        uint4 a0, a1, l0, l1;
        int gr = rowBase + srow;
        if (gr < M) {
            const uint4* pa = (const uint4*)(Ah + (size_t)gr * 512 + k0 + kc);
            a0 = pa[0]; a1 = pa[1];
            const uint4* pl = (const uint4*)(Al + (size_t)gr * 512 + k0 + kc);
            l0 = pl[0]; l1 = pl[1];
        } else {
            a0 = make_uint4(0, 0, 0, 0); a1 = a0; l0 = a0; l1 = a0;
        }
        int gn = colBase + srow;
        const uint4* pb = (const uint4*)(Bh + (size_t)gn * 512 + k0 + kc);
        uint4 b0 = pb[0], b1 = pb[1];
        const uint4* pbl = (const uint4*)(Bl + (size_t)gn * 512 + k0 + kc);
        uint4 bl0 = pbl[0], bl1 = pbl[1];
        __syncthreads();
        *(uint4*)&sAh[srow * LP + kc] = a0; *(uint4*)&sAh[srow * LP + kc + 8] = a1;
        *(uint4*)&sAl[srow * LP + kc] = l0; *(uint4*)&sAl[srow * LP + kc + 8] = l1;
        *(uint4*)&sBh[srow * LP + kc] = b0; *(uint4*)&sBh[srow * LP + kc + 8] = b1;
        *(uint4*)&sBl[srow * LP + kc] = bl0; *(uint4*)&sBl[srow * LP + kc + 8] = bl1;
        __syncthreads();
        bf16x8 afh[4], afl[4], bfh[4], bfl[4];
#pragma unroll
        for (int fr = 0; fr < 4; ++fr) {
            int r = wr + fr * 16 + fl;
            afh[fr] = *(const bf16x8*)&sAh[r * LP + kf];
            afl[fr] = *(const bf16x8*)&sAl[r * LP + kf];
        }
#pragma unroll
        for (int fc = 0; fc < 4; ++fc) {
            int c = wc + fc * 16 + fl;
            bfh[fc] = *(const bf16x8*)&sBh[c * LP + kf];
            bfl[fc] = *(const bf16x8*)&sBl[c * LP + kf];
        }
#pragma unroll
        for (int fr = 0; fr < 4; ++fr) {
#pragma unroll
            for (int fc = 0; fc < 4; ++fc) {
                acc[fr][fc] = __builtin_amdgcn_mfma_f32_16x16x32_bf16(afh[fr], bfh[fc], acc[fr][fc], 0, 0, 0);
                acc[fr][fc] = __builtin_amdgcn_mfma_f32_16x16x32_bf16(afh[fr], bfl[fc], acc[fr][fc], 0, 0, 0);
                acc[fr][fc] = __builtin_amdgcn_mfma_f32_16x16x32_bf16(afl[fr], bfh[fc], acc[fr][fc], 0, 0, 0);
            }
        }
    }
    int orow0 = rowBase + wr + 4 * (lane >> 4);
    int ocol0 = colBase + wc + fl;
#pragma unroll
    for (int fr = 0; fr < 4; ++fr) {
#pragma unroll
        for (int fc = 0; fc < 4; ++fc) {
            int col = ocol0 + fc * 16;
            float bv = bias[col];
#pragma unroll
            for (int j = 0; j < 4; ++j) {
                int row = orow0 + fr * 16 + j;
                if (row < M) out[(size_t)row * ldo + ooff + col] = acc[fr][fc][j] + bv;
            }
        }
    }
}

// ---------------- fused GAT edge pipeline: one block per dst node ----------------
// logits + online segment-softmax + weighted aggregate + head-mean + bias + relu
__global__ __launch_bounds__(256) void k_gat_fused(const float* __restrict__ xlr,
                                                   const int* __restrict__ rowptr,
                                                   const int* __restrict__ csr_src,
                                                   const float* __restrict__ att,
                                                   const float* __restrict__ bias,
                                                   float* __restrict__ out, int N) {
    int d = blockIdx.x;
    if (d >= N) return;
    int t = threadIdx.x;
    int lane = t & 63, wave = t >> 6, h = t >> 7;
    __shared__ float wred[2][4];
    __shared__ float accs[1024];
    float4 xr = *(const float4*)(xlr + (size_t)d * 2048 + 1024 + t * 4);
    float4 at = *(const float4*)(att + t * 4);
    int rs = rowptr[d], re = rowptr[d + 1];
    // self-loop
    float4 xs = *(const float4*)(xlr + (size_t)d * 2048 + t * 4);
    float e0 = xs.x + xr.x; e0 = e0 > 0.f ? e0 : NEGS * e0;
    float e1 = xs.y + xr.y; e1 = e1 > 0.f ? e1 : NEGS * e1;
    float e2 = xs.z + xr.z; e2 = e2 > 0.f ? e2 : NEGS * e2;
    float e3 = xs.w + xr.w; e3 = e3 > 0.f ? e3 : NEGS * e3;
    float p = e0 * at.x + e1 * at.y + e2 * at.z + e3 * at.w;
#pragma unroll
    for (int o = 32; o > 0; o >>= 1) p += __shfl_xor(p, o, 64);
    if (lane == 0) wred[0][wave] = p;
    __syncthreads();
    float m = wred[0][2 * h] + wred[0][2 * h + 1];
    float den = 1.f;
    float ax = xs.x, ay = xs.y, az = xs.z, aw = xs.w;
    int buf = 1;
    for (int e = rs; e < re; ++e) {
        int s = csr_src[e];
        float4 v = *(const float4*)(xlr + (size_t)s * 2048 + t * 4);
        float f0 = v.x + xr.x; f0 = f0 > 0.f ? f0 : NEGS * f0;
        float f1 = v.y + xr.y; f1 = f1 > 0.f ? f1 : NEGS * f1;
        float f2 = v.z + xr.z; f2 = f2 > 0.f ? f2 : NEGS * f2;
        float f3 = v.w + xr.w; f3 = f3 > 0.f ? f3 : NEGS * f3;
        p = f0 * at.x + f1 * at.y + f2 * at.z + f3 * at.w;
#pragma unroll
        for (int o = 32; o > 0; o >>= 1) p += __shfl_xor(p, o, 64);
        if (lane == 0) wred[buf][wave] = p;
        __syncthreads();
        float lg = wred[buf][2 * h] + wred[buf][2 * h + 1];
        buf ^= 1;
        float w;
        if (lg > m) {
            float sc = __expf(m - lg);
            den *= sc; ax *= sc; ay *= sc; az *= sc; aw *= sc;
            m = lg; w = 1.f;
        } else {
            w = __expf(lg - m);
        }
        den += w;
        ax += w * v.x; ay += w * v.y; az += w * v.z; aw += w * v.w;
    }
    float inv = 1.f / fmaxf(den, 1e-16f);
    accs[t * 4 + 0] = ax * inv;
    accs[t * 4 + 1] = ay * inv;
    accs[t * 4 + 2] = az * inv;
    accs[t * 4 + 3] = aw * inv;
    __syncthreads();
    if (t < 128) {
        int c = t * 4;
        float4 bb = *(const float4*)(bias + c);
        float4 r;
        r.x = fmaxf(0.5f * (accs[c + 0] + accs[512 + c + 0]) + bb.x, 0.f);
        r.y = fmaxf(0.5f * (accs[c + 1] + accs[512 + c + 1]) + bb.y, 0.f);
        r.z = fmaxf(0.5f * (accs[c + 2] + accs[512 + c + 2]) + bb.z, 0.f);
        r.w = fmaxf(0.5f * (accs[c + 3] + accs[512 + c + 3]) + bb.w, 0.f);
        *(float4*)(out + (size_t)d * 512 + c) = r;
    }
}

// ---------------- row dots: y0 = x . Wrel, y1 = x . Wroot (wave per node) ----------------
__global__ __launch_bounds__(256) void k_rowdots(const float* __restrict__ x,
                                                 const float* __restrict__ Wrel, const float* __restrict__ Wroot,
                                                 float* __restrict__ y0, float* __restrict__ y1, int N) {
    int d = (blockIdx.x * blockDim.x + threadIdx.x) >> 6;
    int lane = threadIdx.x & 63;
    if (d >= N) return;
    const float* xd = x + (size_t)d * 512 + lane * 8;
    const float* wr = Wrel + lane * 8;
    const float* wo = Wroot + lane * 8;
    float s0 = 0.f, s1 = 0.f;
#pragma unroll
    for (int j = 0; j < 2; ++j) {
        float4 v = *(const float4*)(xd + j * 4);
        float4 a = *(const float4*)(wr + j * 4);
        float4 b = *(const float4*)(wo + j * 4);
        s0 += v.x * a.x + v.y * a.y + v.z * a.z + v.w * a.w;
        s1 += v.x * b.x + v.y * b.y + v.z * b.z + v.w * b.w;
    }
#pragma unroll
    for (int o = 32; o > 0; o >>= 1) {
        s0 += __shfl_xor(s0, o, 64);
        s1 += __shfl_xor(s1, o, 64);
    }
    if (lane == 0) { y0[d] = s0; y1[d] = s1; }
}

// ---------------- score via CSR scalar sums ----------------
__global__ void k_score2(const float* __restrict__ y0, const float* __restrict__ y1,
                         const int* __restrict__ rowptr, const int* __restrict__ csr_src,
                         const float* __restrict__ brel_p,
                         float* __restrict__ score, int N) {
    int d = blockIdx.x * blockDim.x + threadIdx.x;
    if (d >= N) return;
    float s = y1[d] + brel_p[0];
    int rs = rowptr[d], re = rowptr[d + 1];
    for (int e = rs; e < re; ++e) s += y0[csr_src[e]];
    score[d] = s;
}

// ---------------- per-graph top-k via radix select (block per graph) ----------------
__global__ __launch_bounds__(256) void k_topk_radix(const float* __restrict__ score, int ng, int k,
                                                    int* __restrict__ newidx, int* __restrict__ sel_old,
                                                    float* __restrict__ sel_scale) {
    int b = blockIdx.x;
    int t = threadIdx.x;
    __shared__ unsigned int keys[NG0];
    __shared__ int hist[256];
    __shared__ int scnt[256];
    __shared__ unsigned int s_pref, s_amask;
    __shared__ int s_krem, s_gt;
    for (int i = t; i < ng; i += 256) {
        float f = score[b * ng + i];
        unsigned int u = __float_as_uint(f);
        u = (u & 0x80000000u) ? ~u : (u | 0x80000000u);
        keys[i] = u;
        newidx[b * ng + i] = -1;
    }
    if (t == 0) { s_pref = 0u; s_amask = 0u; s_krem = k; s_gt = 0; }
    __syncthreads();
    for (int pass = 0; pass < 4; ++pass) {
        int shift = 24 - 8 * pass;
        hist[t] = 0;
        __syncthreads();
        unsigned int amask = s_amask, pref = s_pref;
        for (int i = t; i < ng; i += 256) {
            unsigned int u = keys[i];
            if ((u & amask) == pref) atomicAdd(&hist[(u >> shift) & 255], 1);
        }
        __syncthreads();
        if (t == 0) {
            int krem = s_krem, cum = 0, dsel = 0;
            for (int dd = 255; dd >= 0; --dd) {
                cum += hist[dd];
                if (cum >= krem) { dsel = dd; krem -= (cum - hist[dd]); break; }
            }
            s_pref = s_pref | ((unsigned int)dsel << shift);
            s_amask = s_amask | (0xFFu << shift);
            s_krem = krem;
        }
        __syncthreads();
    }
    unsigned int T = s_pref;
    int krem = s_krem;
    int chunk = (ng + 255) / 256;
    int lo = t * chunk, hi = min(ng, lo + chunk);
    int ceq = 0;
    for (int i = lo; i < hi; ++i) if (keys[i] == T) ceq++;
    scnt[t] = ceq;
    __syncthreads();
    for (int o = 1; o < 256; o <<= 1) {
        int add = (t >= o) ? scnt[t - o] : 0;
        __syncthreads();
        scnt[t] += add;
        __syncthreads();
    }
    int eq_rank = scnt[t] - ceq;
    for (int i = lo; i < hi; ++i) {
        unsigned int u = keys[i];
        int slot = -1;
        if (u > T) slot = atomicAdd(&s_gt, 1);
        else if (u == T) {
            if (eq_rank < krem) slot = (k - krem) + eq_rank;
            eq_rank++;
        }
        if (slot >= 0) {
            int oldg = b * ng + i;
            int newg = b * k + slot;
            newidx[oldg] = newg;
            sel_old[newg] = oldg;
            sel_scale[newg] = tanhf(score[oldg]);
        }
    }
}

// ---------------- pool gather + tanh scale + bf16 hi/lo split for next GEMM ----------------
__global__ __launch_bounds__(128) void k_pool_cvt(const float* __restrict__ x, const int* __restrict__ sel_old,
                                                  const float* __restrict__ sel_scale, float* __restrict__ xn,
                                                  __bf16* __restrict__ hi, __bf16* __restrict__ lo) {
    int nn = blockIdx.x;
    int so = sel_old[nn];
    float sc = sel_scale[nn];
    int c = threadIdx.x * 4;
    float4 vv = *(const float4*)(x + (size_t)so * 512 + c);
    vv.x *= sc; vv.y *= sc; vv.z *= sc; vv.w *= sc;
    *(float4*)(xn + (size_t)nn * 512 + c) = vv;
    float f[4] = {vv.x, vv.y, vv.z, vv.w};
    bf16x4 vh, vl;
#pragma unroll
    for (int j = 0; j < 4; ++j) {
        __bf16 hh = (__bf16)f[j];
        vh[j] = hh;
        vl[j] = (__bf16)(f[j] - (float)hh);
    }
    *(bf16x4*)(hi + (size_t)nn * 512 + c) = vh;
    *(bf16x4*)(lo + (size_t)nn * 512 + c) = vl;
}

// ---------------- edge remap ----------------
__global__ void k_remap(int* src, int* dst, int* mask, const int* __restrict__ newidx) {
    int e = blockIdx.x * blockDim.x + threadIdx.x;
    if (e >= ETOT) return;
    if (!mask[e]) return;
    int ns = newidx[src[e]];
    int nd = newidx[dst[e]];
    if (ns >= 0 && nd >= 0) { src[e] = ns; dst[e] = nd; }
    else mask[e] = 0;
}

// ---------------- readout phase 1 ----------------
__global__ __launch_bounds__(256) void k_readout_part(const float* __restrict__ x, int k,
                                                      float* __restrict__ pmax, float* __restrict__ psum) {
    int b = blockIdx.x, cg = blockIdx.y, rc = blockIdx.z;
    int t = threadIdx.x;
    int c4 = (t & 63);
    int rl = t >> 6;
    int col = cg * 256 + c4 * 4;
    int rstart = rc * 4 + rl;
    float4 mx = make_float4(-1e30f, -1e30f, -1e30f, -1e30f);
    float4 sm = make_float4(0.f, 0.f, 0.f, 0.f);
    for (int j = rstart; j < k; j += 32) {
        float4 v = *(const float4*)(x + ((size_t)(b * k + j)) * 512 + col);
        mx.x = fmaxf(mx.x, v.x); mx.y = fmaxf(mx.y, v.y); mx.z = fmaxf(mx.z, v.z); mx.w = fmaxf(mx.w, v.w);
        sm.x += v.x; sm.y += v.y; sm.z += v.z; sm.w += v.w;
    }
    __shared__ float lmx[256 * 4];
    __shared__ float lsm[256 * 4];
    int li = c4 * 4 + rl * 256;
    lmx[li + 0] = mx.x; lmx[li + 1] = mx.y; lmx[li + 2] = mx.z; lmx[li + 3] = mx.w;
    lsm[li + 0] = sm.x; lsm[li + 1] = sm.y; lsm[li + 2] = sm.z; lsm[li + 3] = sm.w;
    __syncthreads();
    if (rl == 0) {
        int ci = c4 * 4;
#pragma unroll
        for (int q = 0; q < 4; ++q) {
            float m = fmaxf(fmaxf(lmx[ci + q], lmx[ci + q + 256]), fmaxf(lmx[ci + q + 512], lmx[ci + q + 768]));
            float s = lsm[ci + q] + lsm[ci + q + 256] + lsm[ci + q + 512] + lsm[ci + q + 768];
            size_t o = ((size_t)(b * 8 + rc)) * 512 + col + q;
            pmax[o] = m;
            psum[o] = s;
        }
    }
}

// ---------------- readout phase 2 ----------------
__global__ __launch_bounds__(512) void k_readout_fin(const float* __restrict__ pmax, const float* __restrict__ psum,
                                                     int k, float* __restrict__ readout) {
    int b = blockIdx.x;
    int c = threadIdx.x;
    float m = -1e30f, s = 0.f;
#pragma unroll
    for (int rc = 0; rc < 8; ++rc) {
        size_t o = ((size_t)(b * 8 + rc)) * 512 + c;
        m = fmaxf(m, pmax[o]);
        s += psum[o];
    }
    readout[b * 1024 + c] += m;
    readout[b * 1024 + 512 + c] += s / (float)k;
}

// ---------------- final MLP + softmax ----------------
__global__ __launch_bounds__(512) void k_mlp(const float* __restrict__ readout,
                                             const float* __restrict__ W1, const float* __restrict__ b1,
                                             const float* __restrict__ W2, const float* __restrict__ b2,
                                             const float* __restrict__ W3, const float* __restrict__ b3,
                                             float* __restrict__ out) {
    int b = blockIdx.x;
    int t = threadIdx.x;
    __shared__ float r[1024];
    __shared__ float h1[512];
    __shared__ float h2[256];
    __shared__ float lg[5];
    r[t] = readout[b * 1024 + t];
    r[t + 512] = readout[b * 1024 + 512 + t];
    __syncthreads();
    float s = b1[t];
    for (int i = 0; i < 1024; ++i) s += r[i] * W1[i * 512 + t];
    h1[t] = fmaxf(s, 0.f);
    __syncthreads();
    if (t < 256) {
        float s2 = b2[t];
        for (int i = 0; i < 512; ++i) s2 += h1[i] * W2[i * 256 + t];
        h2[t] = fmaxf(s2, 0.f);
    }
    __syncthreads();
    if (t < 5) {
        float s3 = b3[t];
        for (int i = 0; i < 256; ++i) s3 += h2[i] * W3[i * 5 + t];
        lg[t] = s3;
        out[b * 5 + t] = s3;
    }
    __syncthreads();
    if (t < 5) {
        float m = lg[0];
        for (int i = 1; i < 5; ++i) m = fmaxf(m, lg[i]);
        float den = 0.f;
        for (int i = 0; i < 5; ++i) den += expf(lg[i] - m);
        out[NB * 5 + b * 5 + t] = expf(lg[t] - m) / den;
    }
}

extern "C" void kernel_launch(void* const* d_in, const int* in_sizes, int n_in,
                              void* d_out, int out_size, void* d_ws, size_t ws_size,
                              hipStream_t stream) {
    const float* x0    = (const float*)d_in[0];
    const int*   ei    = (const int*)d_in[1];
    const float* gWl   = (const float*)d_in[2];
    const float* gbl   = (const float*)d_in[3];
    const float* gWr   = (const float*)d_in[4];
    const float* gbr   = (const float*)d_in[5];
    const float* gatt  = (const float*)d_in[6];
    const float* gbias = (const float*)d_in[7];
    const float* sWrel = (const float*)d_in[8];
    const float* sbrel = (const float*)d_in[9];
    const float* sWroot= (const float*)d_in[10];
    const float* W1 = (const float*)d_in[11];
    const float* b1 = (const float*)d_in[12];
    const float* W2 = (const float*)d_in[13];
    const float* b2 = (const float*)d_in[14];
    const float* W3 = (const float*)d_in[15];
    const float* b3 = (const float*)d_in[16];
    float* out = (float*)d_out;

    char* base = (char*)d_ws;
    size_t off = 0;
    auto alloc = [&](size_t bytes) -> void* {
        void* p = base + off;
        off += (bytes + 255) & ~(size_t)255;
        return p;
    };
    int*   s_src   = (int*)alloc((size_t)ETOT * 4);
    int*   s_dst   = (int*)alloc((size_t)ETOT * 4);
    int*   s_mask  = (int*)alloc((size_t)ETOT * 4);
    int*   csr_src = (int*)alloc((size_t)ETOT * 4);
    int*   rowptr  = (int*)alloc((size_t)(h_Ns[0] + 1) * 4);
    int*   cnt     = (int*)alloc((size_t)(h_Ns[0] + 1) * 4);
    float* score   = (float*)alloc((size_t)h_Ns[0] * 4);
    int*   newidx  = (int*)alloc((size_t)h_Ns[0] * 4);
    int*   sel_old = (int*)alloc((size_t)7000 * 4);
    float* sel_scale = (float*)alloc((size_t)7000 * 4);
    float* readout = (float*)alloc((size_t)NB * 1024 * 4);
    float* pmax    = (float*)alloc((size_t)NB * 8 * 512 * 4);
    float* psum    = (float*)alloc((size_t)NB * 8 * 512 * 4);
    float* y0      = (float*)alloc((size_t)h_Ns[0] * 4);
    float* y1      = (float*)alloc((size_t)h_Ns[0] * 4);
    float* xlr     = (float*)alloc((size_t)h_Ns[0] * 2048 * 4);
    float* gatout  = (float*)alloc((size_t)h_Ns[0] * 512 * 4);
    float* xpool   = (float*)alloc((size_t)7000 * 512 * 4);
    __bf16* Ah     = (__bf16*)alloc((size_t)h_Ns[0] * 512 * 2);
    __bf16* Al     = (__bf16*)alloc((size_t)h_Ns[0] * 512 * 2);
    __bf16* WtH    = (__bf16*)alloc((size_t)8 * 1024 * 512 * 2);
    __bf16* WtL    = (__bf16*)alloc((size_t)8 * 1024 * 512 * 2);

    hipMemsetAsync(readout, 0, (size_t)NB * 1024 * 4, stream);
    k_edge_init<<<(ETOT + 255) / 256, 256, 0, stream>>>(ei, s_src, s_dst, s_mask);
    k_cvtWt<<<dim3(32, 16, 8), dim3(32, 8), 0, stream>>>(gWl, gWr, WtH, WtL);
    k_cvtA<<<(h_Ns[0] * 512 / 8 + 255) / 256, 256, 0, stream>>>(x0, Ah, Al, h_Ns[0] * 512);

    for (int i = 0; i < 4; ++i) {
        int N = h_Ns[i], ng = h_ngs[i], k = h_ks[i];
        // CSR by dst
        hipMemsetAsync(cnt, 0, (size_t)(N + 1) * 4, stream);
        k_hist<<<(ETOT + 255) / 256, 256, 0, stream>>>(s_dst, s_mask, cnt);
        k_scan<<<1, 1024, 0, stream>>>(cnt, rowptr, N);
        k_scatter<<<(ETOT + 255) / 256, 256, 0, stream>>>(s_dst, s_src, s_mask, cnt, csr_src);
        // xl | xr GEMMs (bf16x3 MFMA); Ah/Al prepared by cvtA (layer 0) or k_pool_cvt
        dim3 gg((N + 127) / 128, 8);
        k_gemm3<<<gg, 256, 0, stream>>>(Ah, Al, WtH + (size_t)(2 * i) * 1024 * 512, WtL + (size_t)(2 * i) * 1024 * 512,
                                        gbl + (size_t)i * 1024, xlr, N, 2048, 0);
        k_gemm3<<<gg, 256, 0, stream>>>(Ah, Al, WtH + (size_t)(2 * i + 1) * 1024 * 512, WtL + (size_t)(2 * i + 1) * 1024 * 512,
                                        gbr + (size_t)i * 1024, xlr, N, 2048, 1024);
        // fused GAT: logits + online softmax + aggregate + head-mean + bias + relu
        k_gat_fused<<<N, 256, 0, stream>>>(xlr, rowptr, csr_src, gatt + (size_t)i * 1024,
                                           gbias + (size_t)i * 512, gatout, N);
        // SAG score via row dots
        k_rowdots<<<(N + 3) / 4, 256, 0, stream>>>(gatout, sWrel + (size_t)i * 512, sWroot + (size_t)i * 512, y0, y1, N);
        k_score2<<<(N + 255) / 256, 256, 0, stream>>>(y0, y1, rowptr, csr_src, sbrel + i, score, N);
        // top-k per graph (radix select)
        k_topk_radix<<<NB, 256, 0, stream>>>(score, ng, k, newidx, sel_old, sel_scale);
        // pool gather + bf16 split for next layer's GEMM
        k_pool_cvt<<<NB * k, 128, 0, stream>>>(gatout, sel_old, sel_scale, xpool, Ah, Al);
        // edge remap
        k_remap<<<(ETOT + 255) / 256, 256, 0, stream>>>(s_src, s_dst, s_mask, newidx);
        // readout
        k_readout_part<<<dim3(NB, 2, 8), 256, 0, stream>>>(xpool, k, pmax, psum);
        k_readout_fin<<<NB, 512, 0, stream>>>(pmax, psum, k, readout);
    }
    k_mlp<<<NB, 512, 0, stream>>>(readout, W1, b1, W2, b2, W3, b3, out);
}

// Round 5
// 812.485 us; speedup vs baseline: 3.6828x; 1.1108x over previous
//
#include <hip/hip_runtime.h>
#include <math.h>

#define NB   4
#define NG0  2500
#define ETOT 100000
#define CH   512
#define NEGS 0.2f

static const int h_Ns[5]  = {10000, 7000, 4900, 3432, 2404};
static const int h_ngs[4] = {2500, 1750, 1225, 858};
static const int h_ks[4]  = {1750, 1225, 858, 601};

typedef __bf16 bf16x8 __attribute__((ext_vector_type(8)));
typedef __bf16 bf16x4 __attribute__((ext_vector_type(4)));
typedef float  f32x4  __attribute__((ext_vector_type(4)));

// ---------------- edge init ----------------
__global__ void k_edge_init(const int* __restrict__ ei, int* src, int* dst, int* mask) {
    int e = blockIdx.x * blockDim.x + threadIdx.x;
    if (e < ETOT) { src[e] = ei[e]; dst[e] = ei[ETOT + e]; mask[e] = 1; }
}

// ---------------- CSR build ----------------
__global__ void k_hist(const int* __restrict__ dst, const int* __restrict__ mask, int* cnt) {
    int e = blockIdx.x * blockDim.x + threadIdx.x;
    if (e < ETOT && mask[e]) atomicAdd(&cnt[dst[e]], 1);
}

// wave-shuffle hierarchical scan, single block
__global__ __launch_bounds__(1024) void k_scan(int* cnt, int* rowptr, int N) {
    __shared__ int wsum[16];
    __shared__ int s_carry;
    int t = threadIdx.x, lane = t & 63, wave = t >> 6;
    if (t == 0) s_carry = 0;
    __syncthreads();
    for (int base = 0; base < N; base += 1024) {
        int i = base + t;
        int v = (i < N) ? cnt[i] : 0;
        int x = v;
#pragma unroll
        for (int o = 1; o < 64; o <<= 1) {
            int y = __shfl_up(x, o, 64);
            if (lane >= o) x += y;
        }
        if (lane == 63) wsum[wave] = x;
        __syncthreads();
        if (wave == 0) {
            int w = (lane < 16) ? wsum[lane] : 0;
#pragma unroll
            for (int o = 1; o < 16; o <<= 1) {
                int y = __shfl_up(w, o, 64);
                if (lane >= o) w += y;
            }
            if (lane < 16) wsum[lane] = w;
        }
        __syncthreads();
        int woff = wave ? wsum[wave - 1] : 0;
        int rc = s_carry;
        int excl = woff + x - v;
        if (i < N) { int r = rc + excl; rowptr[i] = r; cnt[i] = r; }
        __syncthreads();
        if (t == 0) s_carry = rc + wsum[15];
        __syncthreads();
    }
    if (threadIdx.x == 0) rowptr[N] = s_carry;
}

__global__ void k_scatter(const int* __restrict__ dst, const int* __restrict__ src,
                          const int* __restrict__ mask, int* cursor, int* csr_src) {
    int e = blockIdx.x * blockDim.x + threadIdx.x;
    if (e < ETOT && mask[e]) { int p = atomicAdd(&cursor[dst[e]], 1); csr_src[p] = src[e]; }
}

// ---------------- f32 -> bf16 hi/lo split (layer 0 only) ----------------
__global__ void k_cvtA(const float* __restrict__ x, __bf16* __restrict__ hi,
                       __bf16* __restrict__ lo, int n) {
    int i = (blockIdx.x * blockDim.x + threadIdx.x) * 8;
    if (i >= n) return;
    float4 a = *(const float4*)(x + i);
    float4 b = *(const float4*)(x + i + 4);
    float f[8] = {a.x, a.y, a.z, a.w, b.x, b.y, b.z, b.w};
    bf16x8 vh, vl;
#pragma unroll
    for (int j = 0; j < 8; ++j) {
        __bf16 h = (__bf16)f[j];
        vh[j] = h;
        vl[j] = (__bf16)(f[j] - (float)h);
    }
    *(bf16x8*)(hi + i) = vh;
    *(bf16x8*)(lo + i) = vl;
}

// ---------------- W transpose + split ----------------
__global__ void k_cvtWt(const float* __restrict__ gWl, const float* __restrict__ gWr,
                        __bf16* __restrict__ WtH, __bf16* __restrict__ WtL) {
    int m = blockIdx.z;
    const float* src = ((m & 1) ? gWr : gWl) + (size_t)(m >> 1) * 512 * 1024;
    __bf16* oh = WtH + (size_t)m * 1024 * 512;
    __bf16* ol = WtL + (size_t)m * 1024 * 512;
    int nb = blockIdx.x * 32, kb = blockIdx.y * 32;
    __shared__ float tile[32][33];
#pragma unroll
    for (int j = 0; j < 4; ++j) {
        int kk = threadIdx.y + j * 8;
        tile[kk][threadIdx.x] = src[(size_t)(kb + kk) * 1024 + nb + threadIdx.x];
    }
    __syncthreads();
#pragma unroll
    for (int j = 0; j < 4; ++j) {
        int nn = threadIdx.y + j * 8;
        float v = tile[threadIdx.x][nn];
        __bf16 h = (__bf16)v;
        __bf16 l = (__bf16)(v - (float)h);
        oh[(size_t)(nb + nn) * 512 + kb + threadIdx.x] = h;
        ol[(size_t)(nb + nn) * 512 + kb + threadIdx.x] = l;
    }
}

// ---------------- generic f32 transpose: dst[c][r] = src[r][c] ----------------
__global__ void k_transpose(const float* __restrict__ src, float* __restrict__ dst, int R, int C) {
    __shared__ float tile[32][33];
    int rb = blockIdx.y * 32, cb = blockIdx.x * 32;
#pragma unroll
    for (int j = 0; j < 4; ++j) {
        int r = rb + threadIdx.y + j * 8;
        int c = cb + threadIdx.x;
        if (r < R && c < C) tile[threadIdx.y + j * 8][threadIdx.x] = src[(size_t)r * C + c];
    }
    __syncthreads();
#pragma unroll
    for (int j = 0; j < 4; ++j) {
        int c = cb + threadIdx.y + j * 8;
        int r = rb + threadIdx.x;
        if (r < R && c < C) dst[(size_t)c * R + r] = tile[threadIdx.x][threadIdx.y + j * 8];
    }
}

// ---------------- combined bias [4][2048] = [bl | br] ----------------
__global__ void k_prep_bias(const float* __restrict__ gbl, const float* __restrict__ gbr,
                            float* __restrict__ biasC) {
    int i = blockIdx.x * blockDim.x + threadIdx.x;
    if (i >= 4 * 2048) return;
    int l = i >> 11, c = i & 2047;
    biasC[i] = (c < 1024) ? gbl[l * 1024 + c] : gbr[l * 1024 + c - 1024];
}

// ---------------- bf16x3 MFMA GEMM (combined Wl|Wr: 2048 cols) ----------------
#define LP 40
__global__ __launch_bounds__(256) void k_gemm3(const __bf16* __restrict__ Ah, const __bf16* __restrict__ Al,
                                               const __bf16* __restrict__ Bh, const __bf16* __restrict__ Bl,
                                               const float* __restrict__ bias, float* __restrict__ out,
                                               int M, int ldo) {
    __shared__ __bf16 sAh[128 * LP];
    __shared__ __bf16 sAl[128 * LP];
    __shared__ __bf16 sBh[128 * LP];
    __shared__ __bf16 sBl[128 * LP];
    int tid = threadIdx.x;
    int rowBase = blockIdx.x * 128, colBase = blockIdx.y * 128;
    int wave = tid >> 6, lane = tid & 63;
    int wr = (wave >> 1) * 64, wc = (wave & 1) * 64;
    f32x4 acc[4][4];
#pragma unroll
    for (int a = 0; a < 4; ++a)
#pragma unroll
        for (int b = 0; b < 4; ++b) { acc[a][b][0] = 0.f; acc[a][b][1] = 0.f; acc[a][b][2] = 0.f; acc[a][b][3] = 0.f; }
    int srow = tid >> 1;
    int kc = (tid & 1) * 16;
    int kf = 8 * (lane >> 4);
    int fl = lane & 15;
    for (int k0 = 0; k0 < 512; k0 += 32) {
        uint4 a0, a1, l0, l1;
        int gr = rowBase + srow;
        if (gr < M) {
            const uint4* pa = (const uint4*)(Ah + (size_t)gr * 512 + k0 + kc);
            a0 = pa[0]; a1 = pa[1];
            const uint4* pl = (const uint4*)(Al + (size_t)gr * 512 + k0 + kc);
            l0 = pl[0]; l1 = pl[1];
        } else {
            a0 = make_uint4(0, 0, 0, 0); a1 = a0; l0 = a0; l1 = a0;
        }
        int gn = colBase + srow;
        const uint4* pb = (const uint4*)(Bh + (size_t)gn * 512 + k0 + kc);
        uint4 b0 = pb[0], b1 = pb[1];
        const uint4* pbl = (const uint4*)(Bl + (size_t)gn * 512 + k0 + kc);
        uint4 bl0 = pbl[0], bl1 = pbl[1];
        __syncthreads();
        *(uint4*)&sAh[srow * LP + kc] = a0; *(uint4*)&sAh[srow * LP + kc + 8] = a1;
        *(uint4*)&sAl[srow * LP + kc] = l0; *(uint4*)&sAl[srow * LP + kc + 8] = l1;
        *(uint4*)&sBh[srow * LP + kc] = b0; *(uint4*)&sBh[srow * LP + kc + 8] = b1;
        *(uint4*)&sBl[srow * LP + kc] = bl0; *(uint4*)&sBl[srow * LP + kc + 8] = bl1;
        __syncthreads();
        bf16x8 afh[4], afl[4], bfh[4], bfl[4];
#pragma unroll
        for (int fr = 0; fr < 4; ++fr) {
            int r = wr + fr * 16 + fl;
            afh[fr] = *(const bf16x8*)&sAh[r * LP + kf];
            afl[fr] = *(const bf16x8*)&sAl[r * LP + kf];
        }
#pragma unroll
        for (int fc = 0; fc < 4; ++fc) {
            int c = wc + fc * 16 + fl;
            bfh[fc] = *(const bf16x8*)&sBh[c * LP + kf];
            bfl[fc] = *(const bf16x8*)&sBl[c * LP + kf];
        }
#pragma unroll
        for (int fr = 0; fr < 4; ++fr) {
#pragma unroll
            for (int fc = 0; fc < 4; ++fc) {
                acc[fr][fc] = __builtin_amdgcn_mfma_f32_16x16x32_bf16(afh[fr], bfh[fc], acc[fr][fc], 0, 0, 0);
                acc[fr][fc] = __builtin_amdgcn_mfma_f32_16x16x32_bf16(afh[fr], bfl[fc], acc[fr][fc], 0, 0, 0);
                acc[fr][fc] = __builtin_amdgcn_mfma_f32_16x16x32_bf16(afl[fr], bfh[fc], acc[fr][fc], 0, 0, 0);
            }
        }
    }
    int orow0 = rowBase + wr + 4 * (lane >> 4);
    int ocol0 = colBase + wc + fl;
#pragma unroll
    for (int fr = 0; fr < 4; ++fr) {
#pragma unroll
        for (int fc = 0; fc < 4; ++fc) {
            int col = ocol0 + fc * 16;
            float bv = bias[col];
#pragma unroll
            for (int j = 0; j < 4; ++j) {
                int row = orow0 + fr * 16 + j;
                if (row < M) out[(size_t)row * ldo + col] = acc[fr][fc][j] + bv;
            }
        }
    }
}

// ---------------- fused GAT: one WAVE per dst node, no barriers ----------------
// lane l owns dims [l*16, l*16+16) of the 1024-dim (lanes 0-31 head0, 32-63 head1)
__global__ __launch_bounds__(256) void k_gat_wave(const float* __restrict__ xlr,
                                                  const int* __restrict__ rowptr,
                                                  const int* __restrict__ csr_src,
                                                  const float* __restrict__ att,
                                                  const float* __restrict__ bias,
                                                  float* __restrict__ out, int N) {
    int d = (blockIdx.x * blockDim.x + threadIdx.x) >> 6;
    if (d >= N) return;
    int lane = threadIdx.x & 63;
    int c0 = lane * 16;
    const float* xrp = xlr + (size_t)d * 2048 + 1024 + c0;
    float4 xr0 = *(const float4*)(xrp + 0), xr1 = *(const float4*)(xrp + 4);
    float4 xr2 = *(const float4*)(xrp + 8), xr3 = *(const float4*)(xrp + 12);
    const float* atp = att + c0;
    float4 at0 = *(const float4*)(atp + 0), at1 = *(const float4*)(atp + 4);
    float4 at2 = *(const float4*)(atp + 8), at3 = *(const float4*)(atp + 12);
    float acc[16];
    float m, den;
    // self-loop first
    {
        const float* xsp = xlr + (size_t)d * 2048 + c0;
        float4 v0 = *(const float4*)(xsp + 0), v1 = *(const float4*)(xsp + 4);
        float4 v2 = *(const float4*)(xsp + 8), v3 = *(const float4*)(xsp + 12);
        float p = 0.f, e;
        e = v0.x + xr0.x; e = e > 0.f ? e : NEGS * e; p += e * at0.x;
        e = v0.y + xr0.y; e = e > 0.f ? e : NEGS * e; p += e * at0.y;
        e = v0.z + xr0.z; e = e > 0.f ? e : NEGS * e; p += e * at0.z;
        e = v0.w + xr0.w; e = e > 0.f ? e : NEGS * e; p += e * at0.w;
        e = v1.x + xr1.x; e = e > 0.f ? e : NEGS * e; p += e * at1.x;
        e = v1.y + xr1.y; e = e > 0.f ? e : NEGS * e; p += e * at1.y;
        e = v1.z + xr1.z; e = e > 0.f ? e : NEGS * e; p += e * at1.z;
        e = v1.w + xr1.w; e = e > 0.f ? e : NEGS * e; p += e * at1.w;
        e = v2.x + xr2.x; e = e > 0.f ? e : NEGS * e; p += e * at2.x;
        e = v2.y + xr2.y; e = e > 0.f ? e : NEGS * e; p += e * at2.y;
        e = v2.z + xr2.z; e = e > 0.f ? e : NEGS * e; p += e * at2.z;
        e = v2.w + xr2.w; e = e > 0.f ? e : NEGS * e; p += e * at2.w;
        e = v3.x + xr3.x; e = e > 0.f ? e : NEGS * e; p += e * at3.x;
        e = v3.y + xr3.y; e = e > 0.f ? e : NEGS * e; p += e * at3.y;
        e = v3.z + xr3.z; e = e > 0.f ? e : NEGS * e; p += e * at3.z;
        e = v3.w + xr3.w; e = e > 0.f ? e : NEGS * e; p += e * at3.w;
#pragma unroll
        for (int o = 1; o <= 16; o <<= 1) p += __shfl_xor(p, o, 64);  // per-head (32-lane) sum
        m = p; den = 1.f;
        acc[0] = v0.x; acc[1] = v0.y; acc[2] = v0.z; acc[3] = v0.w;
        acc[4] = v1.x; acc[5] = v1.y; acc[6] = v1.z; acc[7] = v1.w;
        acc[8] = v2.x; acc[9] = v2.y; acc[10] = v2.z; acc[11] = v2.w;
        acc[12] = v3.x; acc[13] = v3.y; acc[14] = v3.z; acc[15] = v3.w;
    }
    int rs = rowptr[d], re = rowptr[d + 1];
    for (int eidx = rs; eidx < re; ++eidx) {
        int s = csr_src[eidx];
        const float* xsp = xlr + (size_t)s * 2048 + c0;
        float4 v0 = *(const float4*)(xsp + 0), v1 = *(const float4*)(xsp + 4);
        float4 v2 = *(const float4*)(xsp + 8), v3 = *(const float4*)(xsp + 12);
        float p = 0.f, e;
        e = v0.x + xr0.x; e = e > 0.f ? e : NEGS * e; p += e * at0.x;
        e = v0.y + xr0.y; e = e > 0.f ? e : NEGS * e; p += e * at0.y;
        e = v0.z + xr0.z; e = e > 0.f ? e : NEGS * e; p += e * at0.z;
        e = v0.w + xr0.w; e = e > 0.f ? e : NEGS * e; p += e * at0.w;
        e = v1.x + xr1.x; e = e > 0.f ? e : NEGS * e; p += e * at1.x;
        e = v1.y + xr1.y; e = e > 0.f ? e : NEGS * e; p += e * at1.y;
        e = v1.z + xr1.z; e = e > 0.f ? e : NEGS * e; p += e * at1.z;
        e = v1.w + xr1.w; e = e > 0.f ? e : NEGS * e; p += e * at1.w;
        e = v2.x + xr2.x; e = e > 0.f ? e : NEGS * e; p += e * at2.x;
        e = v2.y + xr2.y; e = e > 0.f ? e : NEGS * e; p += e * at2.y;
        e = v2.z + xr2.z; e = e > 0.f ? e : NEGS * e; p += e * at2.z;
        e = v2.w + xr2.w; e = e > 0.f ? e : NEGS * e; p += e * at2.w;
        e = v3.x + xr3.x; e = e > 0.f ? e : NEGS * e; p += e * at3.x;
        e = v3.y + xr3.y; e = e > 0.f ? e : NEGS * e; p += e * at3.y;
        e = v3.z + xr3.z; e = e > 0.f ? e : NEGS * e; p += e * at3.z;
        e = v3.w + xr3.w; e = e > 0.f ? e : NEGS * e; p += e * at3.w;
#pragma unroll
        for (int o = 1; o <= 16; o <<= 1) p += __shfl_xor(p, o, 64);
        float nm = fmaxf(m, p);
        float sc = __expf(m - nm);
        float w = __expf(p - nm);
        m = nm;
        den = den * sc + w;
        acc[0] = acc[0] * sc + w * v0.x; acc[1] = acc[1] * sc + w * v0.y;
        acc[2] = acc[2] * sc + w * v0.z; acc[3] = acc[3] * sc + w * v0.w;
        acc[4] = acc[4] * sc + w * v1.x; acc[5] = acc[5] * sc + w * v1.y;
        acc[6] = acc[6] * sc + w * v1.z; acc[7] = acc[7] * sc + w * v1.w;
        acc[8] = acc[8] * sc + w * v2.x; acc[9] = acc[9] * sc + w * v2.y;
        acc[10] = acc[10] * sc + w * v2.z; acc[11] = acc[11] * sc + w * v2.w;
        acc[12] = acc[12] * sc + w * v3.x; acc[13] = acc[13] * sc + w * v3.y;
        acc[14] = acc[14] * sc + w * v3.z; acc[15] = acc[15] * sc + w * v3.w;
    }
    float inv = 1.f / fmaxf(den, 1e-16f);
    // cross-head merge: lane l <-> lane l^32 hold the two heads of the same channel range
    float o16[16];
#pragma unroll
    for (int j = 0; j < 16; ++j) {
        float a = acc[j] * inv;
        float b = __shfl_xor(a, 32, 64);
        o16[j] = 0.5f * (a + b);
    }
    if (lane < 32) {
        const float* bp = bias + c0;
        float* op = out + (size_t)d * 512 + c0;
#pragma unroll
        for (int j = 0; j < 16; j += 4) {
            float4 bb = *(const float4*)(bp + j);
            float4 r;
            r.x = fmaxf(o16[j + 0] + bb.x, 0.f);
            r.y = fmaxf(o16[j + 1] + bb.y, 0.f);
            r.z = fmaxf(o16[j + 2] + bb.z, 0.f);
            r.w = fmaxf(o16[j + 3] + bb.w, 0.f);
            *(float4*)(op + j) = r;
        }
    }
}

// ---------------- row dots ----------------
__global__ __launch_bounds__(256) void k_rowdots(const float* __restrict__ x,
                                                 const float* __restrict__ Wrel, const float* __restrict__ Wroot,
                                                 float* __restrict__ y0, float* __restrict__ y1, int N) {
    int d = (blockIdx.x * blockDim.x + threadIdx.x) >> 6;
    int lane = threadIdx.x & 63;
    if (d >= N) return;
    const float* xd = x + (size_t)d * 512 + lane * 8;
    const float* wr = Wrel + lane * 8;
    const float* wo = Wroot + lane * 8;
    float s0 = 0.f, s1 = 0.f;
#pragma unroll
    for (int j = 0; j < 2; ++j) {
        float4 v = *(const float4*)(xd + j * 4);
        float4 a = *(const float4*)(wr + j * 4);
        float4 b = *(const float4*)(wo + j * 4);
        s0 += v.x * a.x + v.y * a.y + v.z * a.z + v.w * a.w;
        s1 += v.x * b.x + v.y * b.y + v.z * b.z + v.w * b.w;
    }
#pragma unroll
    for (int o = 32; o > 0; o >>= 1) {
        s0 += __shfl_xor(s0, o, 64);
        s1 += __shfl_xor(s1, o, 64);
    }
    if (lane == 0) { y0[d] = s0; y1[d] = s1; }
}

// ---------------- score via CSR scalar sums ----------------
__global__ void k_score2(const float* __restrict__ y0, const float* __restrict__ y1,
                         const int* __restrict__ rowptr, const int* __restrict__ csr_src,
                         const float* __restrict__ brel_p,
                         float* __restrict__ score, int N) {
    int d = blockIdx.x * blockDim.x + threadIdx.x;
    if (d >= N) return;
    float s = y1[d] + brel_p[0];
    int rs = rowptr[d], re = rowptr[d + 1];
    for (int e = rs; e < re; ++e) s += y0[csr_src[e]];
    score[d] = s;
}

// ---------------- per-graph top-k via radix select ----------------
__global__ __launch_bounds__(256) void k_topk_radix(const float* __restrict__ score, int ng, int k,
                                                    int* __restrict__ newidx, int* __restrict__ sel_old,
                                                    float* __restrict__ sel_scale) {
    int b = blockIdx.x;
    int t = threadIdx.x;
    __shared__ unsigned int keys[NG0];
    __shared__ int hist[256];
    __shared__ int scnt[256];
    __shared__ unsigned int s_pref, s_amask;
    __shared__ int s_krem, s_gt;
    for (int i = t; i < ng; i += 256) {
        float f = score[b * ng + i];
        unsigned int u = __float_as_uint(f);
        u = (u & 0x80000000u) ? ~u : (u | 0x80000000u);
        keys[i] = u;
        newidx[b * ng + i] = -1;
    }
    if (t == 0) { s_pref = 0u; s_amask = 0u; s_krem = k; s_gt = 0; }
    __syncthreads();
    for (int pass = 0; pass < 4; ++pass) {
        int shift = 24 - 8 * pass;
        hist[t] = 0;
        __syncthreads();
        unsigned int amask = s_amask, pref = s_pref;
        for (int i = t; i < ng; i += 256) {
            unsigned int u = keys[i];
            if ((u & amask) == pref) atomicAdd(&hist[(u >> shift) & 255], 1);
        }
        __syncthreads();
        if (t == 0) {
            int krem = s_krem, cum = 0, dsel = 0;
            for (int dd = 255; dd >= 0; --dd) {
                cum += hist[dd];
                if (cum >= krem) { dsel = dd; krem -= (cum - hist[dd]); break; }
            }
            s_pref = s_pref | ((unsigned int)dsel << shift);
            s_amask = s_amask | (0xFFu << shift);
            s_krem = krem;
        }
        __syncthreads();
    }
    unsigned int T = s_pref;
    int krem = s_krem;
    int chunk = (ng + 255) / 256;
    int lo = t * chunk, hi = min(ng, lo + chunk);
    int ceq = 0;
    for (int i = lo; i < hi; ++i) if (keys[i] == T) ceq++;
    scnt[t] = ceq;
    __syncthreads();
    for (int o = 1; o < 256; o <<= 1) {
        int add = (t >= o) ? scnt[t - o] : 0;
        __syncthreads();
        scnt[t] += add;
        __syncthreads();
    }
    int eq_rank = scnt[t] - ceq;
    for (int i = lo; i < hi; ++i) {
        unsigned int u = keys[i];
        int slot = -1;
        if (u > T) slot = atomicAdd(&s_gt, 1);
        else if (u == T) {
            if (eq_rank < krem) slot = (k - krem) + eq_rank;
            eq_rank++;
        }
        if (slot >= 0) {
            int oldg = b * ng + i;
            int newg = b * k + slot;
            newidx[oldg] = newg;
            sel_old[newg] = oldg;
            sel_scale[newg] = tanhf(score[oldg]);
        }
    }
}

// ---------------- pool gather + tanh scale + bf16 hi/lo split ----------------
__global__ __launch_bounds__(128) void k_pool_cvt(const float* __restrict__ x, const int* __restrict__ sel_old,
                                                  const float* __restrict__ sel_scale, float* __restrict__ xn,
                                                  __bf16* __restrict__ hi, __bf16* __restrict__ lo) {
    int nn = blockIdx.x;
    int so = sel_old[nn];
    float sc = sel_scale[nn];
    int c = threadIdx.x * 4;
    float4 vv = *(const float4*)(x + (size_t)so * 512 + c);
    vv.x *= sc; vv.y *= sc; vv.z *= sc; vv.w *= sc;
    *(float4*)(xn + (size_t)nn * 512 + c) = vv;
    float f[4] = {vv.x, vv.y, vv.z, vv.w};
    bf16x4 vh, vl;
#pragma unroll
    for (int j = 0; j < 4; ++j) {
        __bf16 hh = (__bf16)f[j];
        vh[j] = hh;
        vl[j] = (__bf16)(f[j] - (float)hh);
    }
    *(bf16x4*)(hi + (size_t)nn * 512 + c) = vh;
    *(bf16x4*)(lo + (size_t)nn * 512 + c) = vl;
}

// ---------------- edge remap ----------------
__global__ void k_remap(int* src, int* dst, int* mask, const int* __restrict__ newidx) {
    int e = blockIdx.x * blockDim.x + threadIdx.x;
    if (e >= ETOT) return;
    if (!mask[e]) return;
    int ns = newidx[src[e]];
    int nd = newidx[dst[e]];
    if (ns >= 0 && nd >= 0) { src[e] = ns; dst[e] = nd; }
    else mask[e] = 0;
}

// ---------------- readout phase 1 ----------------
__global__ __launch_bounds__(256) void k_readout_part(const float* __restrict__ x, int k,
                                                      float* __restrict__ pmax, float* __restrict__ psum) {
    int b = blockIdx.x, cg = blockIdx.y, rc = blockIdx.z;
    int t = threadIdx.x;
    int c4 = (t & 63);
    int rl = t >> 6;
    int col = cg * 256 + c4 * 4;
    int rstart = rc * 4 + rl;
    float4 mx = make_float4(-1e30f, -1e30f, -1e30f, -1e30f);
    float4 sm = make_float4(0.f, 0.f, 0.f, 0.f);
    for (int j = rstart; j < k; j += 32) {
        float4 v = *(const float4*)(x + ((size_t)(b * k + j)) * 512 + col);
        mx.x = fmaxf(mx.x, v.x); mx.y = fmaxf(mx.y, v.y); mx.z = fmaxf(mx.z, v.z); mx.w = fmaxf(mx.w, v.w);
        sm.x += v.x; sm.y += v.y; sm.z += v.z; sm.w += v.w;
    }
    __shared__ float lmx[256 * 4];
    __shared__ float lsm[256 * 4];
    int li = c4 * 4 + rl * 256;
    lmx[li + 0] = mx.x; lmx[li + 1] = mx.y; lmx[li + 2] = mx.z; lmx[li + 3] = mx.w;
    lsm[li + 0] = sm.x; lsm[li + 1] = sm.y; lsm[li + 2] = sm.z; lsm[li + 3] = sm.w;
    __syncthreads();
    if (rl == 0) {
        int ci = c4 * 4;
#pragma unroll
        for (int q = 0; q < 4; ++q) {
            float m = fmaxf(fmaxf(lmx[ci + q], lmx[ci + q + 256]), fmaxf(lmx[ci + q + 512], lmx[ci + q + 768]));
            float s = lsm[ci + q] + lsm[ci + q + 256] + lsm[ci + q + 512] + lsm[ci + q + 768];
            size_t o = ((size_t)(b * 8 + rc)) * 512 + col + q;
            pmax[o] = m;
            psum[o] = s;
        }
    }
}

// ---------------- readout phase 2 ----------------
__global__ __launch_bounds__(512) void k_readout_fin(const float* __restrict__ pmax, const float* __restrict__ psum,
                                                     int k, float* __restrict__ readout) {
    int b = blockIdx.x;
    int c = threadIdx.x;
    float m = -1e30f, s = 0.f;
#pragma unroll
    for (int rc = 0; rc < 8; ++rc) {
        size_t o = ((size_t)(b * 8 + rc)) * 512 + c;
        m = fmaxf(m, pmax[o]);
        s += psum[o];
    }
    readout[b * 1024 + c] += m;
    readout[b * 1024 + 512 + c] += s / (float)k;
}

// ---------------- MLP stage 1: h1[b][col] = relu(r[b] . W1t[col] + b1[col]) ----------------
// one wave per (b,col); 2048 waves -> 512 blocks
__global__ __launch_bounds__(256) void k_mlp1(const float* __restrict__ readout, const float* __restrict__ W1t,
                                              const float* __restrict__ b1, float* __restrict__ h1) {
    int wid = (blockIdx.x * blockDim.x + threadIdx.x) >> 6;
    int lane = threadIdx.x & 63;
    int b = wid >> 9, col = wid & 511;
    const float* rp = readout + b * 1024 + lane * 16;
    const float* wp = W1t + (size_t)col * 1024 + lane * 16;
    float s = 0.f;
#pragma unroll
    for (int j = 0; j < 4; ++j) {
        float4 v = *(const float4*)(rp + j * 4);
        float4 w = *(const float4*)(wp + j * 4);
        s += v.x * w.x + v.y * w.y + v.z * w.z + v.w * w.w;
    }
#pragma unroll
    for (int o = 32; o > 0; o >>= 1) s += __shfl_xor(s, o, 64);
    if (lane == 0) h1[b * 512 + col] = fmaxf(s + b1[col], 0.f);
}

// ---------------- MLP stage 2: h2[b][col] = relu(h1[b] . W2t[col] + b2[col]) ----------------
// one wave per (b,col); 1024 waves -> 256 blocks
__global__ __launch_bounds__(256) void k_mlp2(const float* __restrict__ h1, const float* __restrict__ W2t,
                                              const float* __restrict__ b2, float* __restrict__ h2) {
    int wid = (blockIdx.x * blockDim.x + threadIdx.x) >> 6;
    int lane = threadIdx.x & 63;
    int b = wid >> 8, col = wid & 255;
    const float* hp = h1 + b * 512 + lane * 8;
    const float* wp = W2t + (size_t)col * 512 + lane * 8;
    float s = 0.f;
#pragma unroll
    for (int j = 0; j < 2; ++j) {
        float4 v = *(const float4*)(hp + j * 4);
        float4 w = *(const float4*)(wp + j * 4);
        s += v.x * w.x + v.y * w.y + v.z * w.z + v.w * w.w;
    }
#pragma unroll
    for (int o = 32; o > 0; o >>= 1) s += __shfl_xor(s, o, 64);
    if (lane == 0) h2[b * 256 + col] = fmaxf(s + b2[col], 0.f);
}

// ---------------- MLP stage 3: logits + softmax (one wave per graph) ----------------
__global__ __launch_bounds__(256) void k_mlp3(const float* __restrict__ h2, const float* __restrict__ W3,
                                              const float* __restrict__ b3, float* __restrict__ out) {
    int b = threadIdx.x >> 6;
    int lane = threadIdx.x & 63;
    float hv[4];
    int idx[4];
#pragma unroll
    for (int j = 0; j < 4; ++j) { idx[j] = lane + j * 64; hv[j] = h2[b * 256 + idx[j]]; }
    float lg[5];
#pragma unroll
    for (int q = 0; q < 5; ++q) {
        float p = 0.f;
#pragma unroll
        for (int j = 0; j < 4; ++j) p += hv[j] * W3[idx[j] * 5 + q];
#pragma unroll
        for (int o = 32; o > 0; o >>= 1) p += __shfl_xor(p, o, 64);
        lg[q] = p + b3[q];
    }
    if (lane == 0) {
        float m = lg[0];
#pragma unroll
        for (int q = 1; q < 5; ++q) m = fmaxf(m, lg[q]);
        float den = 0.f;
#pragma unroll
        for (int q = 0; q < 5; ++q) den += __expf(lg[q] - m);
#pragma unroll
        for (int q = 0; q < 5; ++q) {
            out[b * 5 + q] = lg[q];
            out[NB * 5 + b * 5 + q] = __expf(lg[q] - m) / den;
        }
    }
}

extern "C" void kernel_launch(void* const* d_in, const int* in_sizes, int n_in,
                              void* d_out, int out_size, void* d_ws, size_t ws_size,
                              hipStream_t stream) {
    const float* x0    = (const float*)d_in[0];
    const int*   ei    = (const int*)d_in[1];
    const float* gWl   = (const float*)d_in[2];
    const float* gbl   = (const float*)d_in[3];
    const float* gWr   = (const float*)d_in[4];
    const float* gbr   = (const float*)d_in[5];
    const float* gatt  = (const float*)d_in[6];
    const float* gbias = (const float*)d_in[7];
    const float* sWrel = (const float*)d_in[8];
    const float* sbrel = (const float*)d_in[9];
    const float* sWroot= (const float*)d_in[10];
    const float* W1 = (const float*)d_in[11];
    const float* b1 = (const float*)d_in[12];
    const float* W2 = (const float*)d_in[13];
    const float* b2 = (const float*)d_in[14];
    const float* W3 = (const float*)d_in[15];
    const float* b3 = (const float*)d_in[16];
    float* out = (float*)d_out;

    char* base = (char*)d_ws;
    size_t off = 0;
    auto alloc = [&](size_t bytes) -> void* {
        void* p = base + off;
        off += (bytes + 255) & ~(size_t)255;
        return p;
    };
    int*   s_src   = (int*)alloc((size_t)ETOT * 4);
    int*   s_dst   = (int*)alloc((size_t)ETOT * 4);
    int*   s_mask  = (int*)alloc((size_t)ETOT * 4);
    int*   csr_src = (int*)alloc((size_t)ETOT * 4);
    int*   rowptr  = (int*)alloc((size_t)(h_Ns[0] + 1) * 4);
    int*   cnt     = (int*)alloc((size_t)(h_Ns[0] + 1) * 4);
    float* score   = (float*)alloc((size_t)h_Ns[0] * 4);
    int*   newidx  = (int*)alloc((size_t)h_Ns[0] * 4);
    int*   sel_old = (int*)alloc((size_t)7000 * 4);
    float* sel_scale = (float*)alloc((size_t)7000 * 4);
    float* readout = (float*)alloc((size_t)NB * 1024 * 4);
    float* pmax    = (float*)alloc((size_t)NB * 8 * 512 * 4);
    float* psum    = (float*)alloc((size_t)NB * 8 * 512 * 4);
    float* y0      = (float*)alloc((size_t)h_Ns[0] * 4);
    float* y1      = (float*)alloc((size_t)h_Ns[0] * 4);
    float* xlr     = (float*)alloc((size_t)h_Ns[0] * 2048 * 4);
    float* gatout  = (float*)alloc((size_t)h_Ns[0] * 512 * 4);
    float* xpool   = (float*)alloc((size_t)7000 * 512 * 4);
    __bf16* Ah     = (__bf16*)alloc((size_t)h_Ns[0] * 512 * 2);
    __bf16* Al     = (__bf16*)alloc((size_t)h_Ns[0] * 512 * 2);
    __bf16* WtH    = (__bf16*)alloc((size_t)8 * 1024 * 512 * 2);
    __bf16* WtL    = (__bf16*)alloc((size_t)8 * 1024 * 512 * 2);
    float* biasC   = (float*)alloc((size_t)4 * 2048 * 4);
    float* W1t     = (float*)alloc((size_t)512 * 1024 * 4);
    float* W2t     = (float*)alloc((size_t)256 * 512 * 4);
    float* h1b     = (float*)alloc((size_t)NB * 512 * 4);
    float* h2b     = (float*)alloc((size_t)NB * 256 * 4);

    hipMemsetAsync(readout, 0, (size_t)NB * 1024 * 4, stream);
    k_edge_init<<<(ETOT + 255) / 256, 256, 0, stream>>>(ei, s_src, s_dst, s_mask);
    k_cvtWt<<<dim3(32, 16, 8), dim3(32, 8), 0, stream>>>(gWl, gWr, WtH, WtL);
    k_cvtA<<<(h_Ns[0] * 512 / 8 + 255) / 256, 256, 0, stream>>>(x0, Ah, Al, h_Ns[0] * 512);
    k_prep_bias<<<(4 * 2048 + 255) / 256, 256, 0, stream>>>(gbl, gbr, biasC);
    k_transpose<<<dim3(16, 32), dim3(32, 8), 0, stream>>>(W1, W1t, 1024, 512);
    k_transpose<<<dim3(8, 16), dim3(32, 8), 0, stream>>>(W2, W2t, 512, 256);

    for (int i = 0; i < 4; ++i) {
        int N = h_Ns[i], ng = h_ngs[i], k = h_ks[i];
        // CSR by dst
        hipMemsetAsync(cnt, 0, (size_t)(N + 1) * 4, stream);
        k_hist<<<(ETOT + 255) / 256, 256, 0, stream>>>(s_dst, s_mask, cnt);
        k_scan<<<1, 1024, 0, stream>>>(cnt, rowptr, N);
        k_scatter<<<(ETOT + 255) / 256, 256, 0, stream>>>(s_dst, s_src, s_mask, cnt, csr_src);
        // combined xl|xr GEMM (bf16x3 MFMA, 2048 cols)
        dim3 gg((N + 127) / 128, 16);
        k_gemm3<<<gg, 256, 0, stream>>>(Ah, Al, WtH + (size_t)(2 * i) * 1024 * 512, WtL + (size_t)(2 * i) * 1024 * 512,
                                        biasC + (size_t)i * 2048, xlr, N, 2048);
        // fused GAT: wave per node
        k_gat_wave<<<(N + 3) / 4, 256, 0, stream>>>(xlr, rowptr, csr_src, gatt + (size_t)i * 1024,
                                                    gbias + (size_t)i * 512, gatout, N);
        // SAG score
        k_rowdots<<<(N + 3) / 4, 256, 0, stream>>>(gatout, sWrel + (size_t)i * 512, sWroot + (size_t)i * 512, y0, y1, N);
        k_score2<<<(N + 255) / 256, 256, 0, stream>>>(y0, y1, rowptr, csr_src, sbrel + i, score, N);
        // top-k per graph
        k_topk_radix<<<NB, 256, 0, stream>>>(score, ng, k, newidx, sel_old, sel_scale);
        // pool gather + bf16 split for next layer
        k_pool_cvt<<<NB * k, 128, 0, stream>>>(gatout, sel_old, sel_scale, xpool, Ah, Al);
        // edge remap
        k_remap<<<(ETOT + 255) / 256, 256, 0, stream>>>(s_src, s_dst, s_mask, newidx);
        // readout
        k_readout_part<<<dim3(NB, 2, 8), 256, 0, stream>>>(xpool, k, pmax, psum);
        k_readout_fin<<<NB, 512, 0, stream>>>(pmax, psum, k, readout);
    }
    // MLP head (wave-parallel stages)
    k_mlp1<<<512, 256, 0, stream>>>(readout, W1t, b1, h1b);
    k_mlp2<<<256, 256, 0, stream>>>(h1b, W2t, b2, h2b);
    k_mlp3<<<1, 256, 0, stream>>>(h2b, W3, b3, out);
}

// Round 6
// 775.176 us; speedup vs baseline: 3.8600x; 1.0481x over previous
//
#include <hip/hip_runtime.h>
#include <math.h>

#define NB   4
#define NG0  2500
#define ETOT 100000
#define CH   512
#define NEGS 0.2f

static const int h_Ns[5]  = {10000, 7000, 4900, 3432, 2404};
static const int h_ngs[4] = {2500, 1750, 1225, 858};
static const int h_ks[4]  = {1750, 1225, 858, 601};

typedef __bf16 bf16x8 __attribute__((ext_vector_type(8)));
typedef __bf16 bf16x4 __attribute__((ext_vector_type(4)));
typedef float  f32x4  __attribute__((ext_vector_type(4)));

#define GLOAD16(g, l)                                                              \
    __builtin_amdgcn_global_load_lds(                                              \
        (const __attribute__((address_space(1))) unsigned int*)(g),                \
        (__attribute__((address_space(3))) unsigned int*)(l), 16, 0, 0)

// ---------------- layer-0: edge init + histogram ----------------
__global__ void k_init_hist(const int* __restrict__ ei, int* src, int* dst, int* mask, int* cnt) {
    int e = blockIdx.x * blockDim.x + threadIdx.x;
    if (e >= ETOT) return;
    int s = ei[e], d = ei[ETOT + e];
    src[e] = s; dst[e] = d; mask[e] = 1;
    atomicAdd(&cnt[d], 1);
}

// ---------------- layer>0: remap + histogram fused ----------------
__global__ void k_remap_hist(int* src, int* dst, int* mask, const int* __restrict__ newidx, int* cnt) {
    int e = blockIdx.x * blockDim.x + threadIdx.x;
    if (e >= ETOT) return;
    if (!mask[e]) return;
    int ns = newidx[src[e]];
    int nd = newidx[dst[e]];
    if (ns >= 0 && nd >= 0) { src[e] = ns; dst[e] = nd; atomicAdd(&cnt[nd], 1); }
    else mask[e] = 0;
}

// wave-shuffle hierarchical scan, single block
__global__ __launch_bounds__(1024) void k_scan(int* cnt, int* rowptr, int N) {
    __shared__ int wsum[16];
    __shared__ int s_carry;
    int t = threadIdx.x, lane = t & 63, wave = t >> 6;
    if (t == 0) s_carry = 0;
    __syncthreads();
    for (int base = 0; base < N; base += 1024) {
        int i = base + t;
        int v = (i < N) ? cnt[i] : 0;
        int x = v;
#pragma unroll
        for (int o = 1; o < 64; o <<= 1) {
            int y = __shfl_up(x, o, 64);
            if (lane >= o) x += y;
        }
        if (lane == 63) wsum[wave] = x;
        __syncthreads();
        if (wave == 0) {
            int w = (lane < 16) ? wsum[lane] : 0;
#pragma unroll
            for (int o = 1; o < 16; o <<= 1) {
                int y = __shfl_up(w, o, 64);
                if (lane >= o) w += y;
            }
            if (lane < 16) wsum[lane] = w;
        }
        __syncthreads();
        int woff = wave ? wsum[wave - 1] : 0;
        int rc = s_carry;
        int excl = woff + x - v;
        if (i < N) { int r = rc + excl; rowptr[i] = r; cnt[i] = r; }
        __syncthreads();
        if (t == 0) s_carry = rc + wsum[15];
        __syncthreads();
    }
    if (threadIdx.x == 0) rowptr[N] = s_carry;
}

__global__ void k_scatter(const int* __restrict__ dst, const int* __restrict__ src,
                          const int* __restrict__ mask, int* cursor, int* csr_src) {
    int e = blockIdx.x * blockDim.x + threadIdx.x;
    if (e < ETOT && mask[e]) { int p = atomicAdd(&cursor[dst[e]], 1); csr_src[p] = src[e]; }
}

// ---------------- f32 -> bf16 hi/lo split (layer 0 only) ----------------
__global__ void k_cvtA(const float* __restrict__ x, __bf16* __restrict__ hi,
                       __bf16* __restrict__ lo, int n) {
    int i = (blockIdx.x * blockDim.x + threadIdx.x) * 8;
    if (i >= n) return;
    float4 a = *(const float4*)(x + i);
    float4 b = *(const float4*)(x + i + 4);
    float f[8] = {a.x, a.y, a.z, a.w, b.x, b.y, b.z, b.w};
    bf16x8 vh, vl;
#pragma unroll
    for (int j = 0; j < 8; ++j) {
        __bf16 h = (__bf16)f[j];
        vh[j] = h;
        vl[j] = (__bf16)(f[j] - (float)h);
    }
    *(bf16x8*)(hi + i) = vh;
    *(bf16x8*)(lo + i) = vl;
}

// ---------------- W transpose + split ----------------
__global__ void k_cvtWt(const float* __restrict__ gWl, const float* __restrict__ gWr,
                        __bf16* __restrict__ WtH, __bf16* __restrict__ WtL) {
    int m = blockIdx.z;
    const float* src = ((m & 1) ? gWr : gWl) + (size_t)(m >> 1) * 512 * 1024;
    __bf16* oh = WtH + (size_t)m * 1024 * 512;
    __bf16* ol = WtL + (size_t)m * 1024 * 512;
    int nb = blockIdx.x * 32, kb = blockIdx.y * 32;
    __shared__ float tile[32][33];
#pragma unroll
    for (int j = 0; j < 4; ++j) {
        int kk = threadIdx.y + j * 8;
        tile[kk][threadIdx.x] = src[(size_t)(kb + kk) * 1024 + nb + threadIdx.x];
    }
    __syncthreads();
#pragma unroll
    for (int j = 0; j < 4; ++j) {
        int nn = threadIdx.y + j * 8;
        float v = tile[threadIdx.x][nn];
        __bf16 h = (__bf16)v;
        __bf16 l = (__bf16)(v - (float)h);
        oh[(size_t)(nb + nn) * 512 + kb + threadIdx.x] = h;
        ol[(size_t)(nb + nn) * 512 + kb + threadIdx.x] = l;
    }
}

// ---------------- generic f32 transpose ----------------
__global__ void k_transpose(const float* __restrict__ src, float* __restrict__ dst, int R, int C) {
    __shared__ float tile[32][33];
    int rb = blockIdx.y * 32, cb = blockIdx.x * 32;
#pragma unroll
    for (int j = 0; j < 4; ++j) {
        int r = rb + threadIdx.y + j * 8;
        int c = cb + threadIdx.x;
        if (r < R && c < C) tile[threadIdx.y + j * 8][threadIdx.x] = src[(size_t)r * C + c];
    }
    __syncthreads();
#pragma unroll
    for (int j = 0; j < 4; ++j) {
        int c = cb + threadIdx.y + j * 8;
        int r = rb + threadIdx.x;
        if (r < R && c < C) dst[(size_t)c * R + r] = tile[threadIdx.x][threadIdx.y + j * 8];
    }
}

// ---------------- combined bias [4][2048] = [bl | br] ----------------
__global__ void k_prep_bias(const float* __restrict__ gbl, const float* __restrict__ gbr,
                            float* __restrict__ biasC) {
    int i = blockIdx.x * blockDim.x + threadIdx.x;
    if (i >= 4 * 2048) return;
    int l = i >> 11, c = i & 2047;
    biasC[i] = (c < 1024) ? gbl[l * 1024 + c] : gbr[l * 1024 + c - 1024];
}

// ---------------- bf16x3 MFMA GEMM with global_load_lds + swizzled LDS ----------------
// LDS tile [128 rows][32 k-elems]; element (r,k): phys slot = (k/8) ^ ((r>>1)&3)
__global__ __launch_bounds__(256) void k_gemm3(const __bf16* __restrict__ Ah, const __bf16* __restrict__ Al,
                                               const __bf16* __restrict__ Bh, const __bf16* __restrict__ Bl,
                                               const float* __restrict__ bias, float* __restrict__ out,
                                               int M, int ldo) {
    __shared__ __bf16 sAh[128 * 32];
    __shared__ __bf16 sAl[128 * 32];
    __shared__ __bf16 sBh[128 * 32];
    __shared__ __bf16 sBl[128 * 32];
    int tid = threadIdx.x;
    // grouped grid swizzle: 8 row-panels x 16 col-panels per group
    int nRows = (M + 127) >> 7;
    int pid = blockIdx.x;
    int fullG = nRows >> 3;
    int inFull = fullG << 7;   // fullG * 8 * 16
    int rowT, colT;
    if (pid < inFull) {
        int g = pid >> 7, r = pid & 127;
        rowT = (g << 3) + (r & 7);
        colT = r >> 3;
    } else {
        int r = pid - inFull;
        int tail = nRows - (fullG << 3);
        rowT = (fullG << 3) + r % tail;
        colT = r / tail;
    }
    int rowBase = rowT << 7, colBase = colT << 7;
    int wave = tid >> 6, lane = tid & 63;
    int wr = (wave >> 1) * 64, wc = (wave & 1) * 64;
    f32x4 acc[4][4];
#pragma unroll
    for (int a = 0; a < 4; ++a)
#pragma unroll
        for (int b = 0; b < 4; ++b) { acc[a][b][0] = 0.f; acc[a][b][1] = 0.f; acc[a][b][2] = 0.f; acc[a][b][3] = 0.f; }

    int srow0 = tid >> 2;     // 0..63
    int ps = tid & 3;
    auto stage = [&](int k0) {
#pragma unroll
        for (int c = 0; c < 2; ++c) {
            int row = (c << 6) + srow0;            // tile row 0..127
            int ls = ps ^ ((row >> 1) & 3);        // logical slot to fetch
            int ldsoff = c * 2048 + tid * 8;       // elems (= bytes/2)
            int grA = rowBase + row; if (grA >= M) grA = M - 1;
            int gnB = colBase + row;
            const __bf16* gah = Ah + (size_t)grA * 512 + k0 + ls * 8;
            const __bf16* gal = Al + (size_t)grA * 512 + k0 + ls * 8;
            const __bf16* gbh = Bh + (size_t)gnB * 512 + k0 + ls * 8;
            const __bf16* gbl2 = Bl + (size_t)gnB * 512 + k0 + ls * 8;
            GLOAD16(gah, &sAh[ldsoff]);
            GLOAD16(gal, &sAl[ldsoff]);
            GLOAD16(gbh, &sBh[ldsoff]);
            GLOAD16(gbl2, &sBl[ldsoff]);
        }
    };

    int fl = lane & 15, g = lane >> 4;
    stage(0);
    __syncthreads();
    for (int ks = 0; ks < 16; ++ks) {
        bf16x8 afh[4], afl[4], bfh[4], bfl[4];
#pragma unroll
        for (int fr = 0; fr < 4; ++fr) {
            int r = wr + fr * 16 + fl;
            int po = (g ^ ((r >> 1) & 3)) << 3;
            afh[fr] = *(const bf16x8*)&sAh[r * 32 + po];
            afl[fr] = *(const bf16x8*)&sAl[r * 32 + po];
        }
#pragma unroll
        for (int fc = 0; fc < 4; ++fc) {
            int cc = wc + fc * 16 + fl;
            int po = (g ^ ((cc >> 1) & 3)) << 3;
            bfh[fc] = *(const bf16x8*)&sBh[cc * 32 + po];
            bfl[fc] = *(const bf16x8*)&sBl[cc * 32 + po];
        }
        __syncthreads();                    // all frags in regs; LDS free
        if (ks < 15) stage((ks + 1) * 32);  // async prefetch under MFMAs
#pragma unroll
        for (int fr = 0; fr < 4; ++fr) {
#pragma unroll
            for (int fc = 0; fc < 4; ++fc) {
                acc[fr][fc] = __builtin_amdgcn_mfma_f32_16x16x32_bf16(afh[fr], bfh[fc], acc[fr][fc], 0, 0, 0);
                acc[fr][fc] = __builtin_amdgcn_mfma_f32_16x16x32_bf16(afh[fr], bfl[fc], acc[fr][fc], 0, 0, 0);
                acc[fr][fc] = __builtin_amdgcn_mfma_f32_16x16x32_bf16(afl[fr], bfh[fc], acc[fr][fc], 0, 0, 0);
            }
        }
        __syncthreads();                    // staging complete (vmcnt drained)
    }
    int orow0 = rowBase + wr + 4 * (lane >> 4);
    int ocol0 = colBase + wc + fl;
#pragma unroll
    for (int fr = 0; fr < 4; ++fr) {
#pragma unroll
        for (int fc = 0; fc < 4; ++fc) {
            int col = ocol0 + fc * 16;
            float bv = bias[col];
#pragma unroll
            for (int j = 0; j < 4; ++j) {
                int row = orow0 + fr * 16 + j;
                if (row < M) out[(size_t)row * ldo + col] = acc[fr][fc][j] + bv;
            }
        }
    }
}

// ---------------- fused GAT: one WAVE per dst node + SAG row-dot epilogue ----------------
__global__ __launch_bounds__(256) void k_gat_wave(const float* __restrict__ xlr,
                                                  const int* __restrict__ rowptr,
                                                  const int* __restrict__ csr_src,
                                                  const float* __restrict__ att,
                                                  const float* __restrict__ bias,
                                                  const float* __restrict__ Wrel,
                                                  const float* __restrict__ Wroot,
                                                  float* __restrict__ out,
                                                  float* __restrict__ y0, float* __restrict__ y1, int N) {
    int d = (blockIdx.x * blockDim.x + threadIdx.x) >> 6;
    if (d >= N) return;
    int lane = threadIdx.x & 63;
    int c0 = lane * 16;
    const float* xrp = xlr + (size_t)d * 2048 + 1024 + c0;
    float4 xr0 = *(const float4*)(xrp + 0), xr1 = *(const float4*)(xrp + 4);
    float4 xr2 = *(const float4*)(xrp + 8), xr3 = *(const float4*)(xrp + 12);
    const float* atp = att + c0;
    float4 at0 = *(const float4*)(atp + 0), at1 = *(const float4*)(atp + 4);
    float4 at2 = *(const float4*)(atp + 8), at3 = *(const float4*)(atp + 12);
    float acc[16];
    float m, den;
    {
        const float* xsp = xlr + (size_t)d * 2048 + c0;
        float4 v0 = *(const float4*)(xsp + 0), v1 = *(const float4*)(xsp + 4);
        float4 v2 = *(const float4*)(xsp + 8), v3 = *(const float4*)(xsp + 12);
        float p = 0.f, e;
        e = v0.x + xr0.x; e = e > 0.f ? e : NEGS * e; p += e * at0.x;
        e = v0.y + xr0.y; e = e > 0.f ? e : NEGS * e; p += e * at0.y;
        e = v0.z + xr0.z; e = e > 0.f ? e : NEGS * e; p += e * at0.z;
        e = v0.w + xr0.w; e = e > 0.f ? e : NEGS * e; p += e * at0.w;
        e = v1.x + xr1.x; e = e > 0.f ? e : NEGS * e; p += e * at1.x;
        e = v1.y + xr1.y; e = e > 0.f ? e : NEGS * e; p += e * at1.y;
        e = v1.z + xr1.z; e = e > 0.f ? e : NEGS * e; p += e * at1.z;
        e = v1.w + xr1.w; e = e > 0.f ? e : NEGS * e; p += e * at1.w;
        e = v2.x + xr2.x; e = e > 0.f ? e : NEGS * e; p += e * at2.x;
        e = v2.y + xr2.y; e = e > 0.f ? e : NEGS * e; p += e * at2.y;
        e = v2.z + xr2.z; e = e > 0.f ? e : NEGS * e; p += e * at2.z;
        e = v2.w + xr2.w; e = e > 0.f ? e : NEGS * e; p += e * at2.w;
        e = v3.x + xr3.x; e = e > 0.f ? e : NEGS * e; p += e * at3.x;
        e = v3.y + xr3.y; e = e > 0.f ? e : NEGS * e; p += e * at3.y;
        e = v3.z + xr3.z; e = e > 0.f ? e : NEGS * e; p += e * at3.z;
        e = v3.w + xr3.w; e = e > 0.f ? e : NEGS * e; p += e * at3.w;
#pragma unroll
        for (int o = 1; o <= 16; o <<= 1) p += __shfl_xor(p, o, 64);
        m = p; den = 1.f;
        acc[0] = v0.x; acc[1] = v0.y; acc[2] = v0.z; acc[3] = v0.w;
        acc[4] = v1.x; acc[5] = v1.y; acc[6] = v1.z; acc[7] = v1.w;
        acc[8] = v2.x; acc[9] = v2.y; acc[10] = v2.z; acc[11] = v2.w;
        acc[12] = v3.x; acc[13] = v3.y; acc[14] = v3.z; acc[15] = v3.w;
    }
    int rs = rowptr[d], re = rowptr[d + 1];
    for (int eidx = rs; eidx < re; ++eidx) {
        int s = csr_src[eidx];
        const float* xsp = xlr + (size_t)s * 2048 + c0;
        float4 v0 = *(const float4*)(xsp + 0), v1 = *(const float4*)(xsp + 4);
        float4 v2 = *(const float4*)(xsp + 8), v3 = *(const float4*)(xsp + 12);
        float p = 0.f, e;
        e = v0.x + xr0.x; e = e > 0.f ? e : NEGS * e; p += e * at0.x;
        e = v0.y + xr0.y; e = e > 0.f ? e : NEGS * e; p += e * at0.y;
        e = v0.z + xr0.z; e = e > 0.f ? e : NEGS * e; p += e * at0.z;
        e = v0.w + xr0.w; e = e > 0.f ? e : NEGS * e; p += e * at0.w;
        e = v1.x + xr1.x; e = e > 0.f ? e : NEGS * e; p += e * at1.x;
        e = v1.y + xr1.y; e = e > 0.f ? e : NEGS * e; p += e * at1.y;
        e = v1.z + xr1.z; e = e > 0.f ? e : NEGS * e; p += e * at1.z;
        e = v1.w + xr1.w; e = e > 0.f ? e : NEGS * e; p += e * at1.w;
        e = v2.x + xr2.x; e = e > 0.f ? e : NEGS * e; p += e * at2.x;
        e = v2.y + xr2.y; e = e > 0.f ? e : NEGS * e; p += e * at2.y;
        e = v2.z + xr2.z; e = e > 0.f ? e : NEGS * e; p += e * at2.z;
        e = v2.w + xr2.w; e = e > 0.f ? e : NEGS * e; p += e * at2.w;
        e = v3.x + xr3.x; e = e > 0.f ? e : NEGS * e; p += e * at3.x;
        e = v3.y + xr3.y; e = e > 0.f ? e : NEGS * e; p += e * at3.y;
        e = v3.z + xr3.z; e = e > 0.f ? e : NEGS * e; p += e * at3.z;
        e = v3.w + xr3.w; e = e > 0.f ? e : NEGS * e; p += e * at3.w;
#pragma unroll
        for (int o = 1; o <= 16; o <<= 1) p += __shfl_xor(p, o, 64);
        float nm = fmaxf(m, p);
        float sc = __expf(m - nm);
        float w = __expf(p - nm);
        m = nm;
        den = den * sc + w;
        acc[0] = acc[0] * sc + w * v0.x; acc[1] = acc[1] * sc + w * v0.y;
        acc[2] = acc[2] * sc + w * v0.z; acc[3] = acc[3] * sc + w * v0.w;
        acc[4] = acc[4] * sc + w * v1.x; acc[5] = acc[5] * sc + w * v1.y;
        acc[6] = acc[6] * sc + w * v1.z; acc[7] = acc[7] * sc + w * v1.w;
        acc[8] = acc[8] * sc + w * v2.x; acc[9] = acc[9] * sc + w * v2.y;
        acc[10] = acc[10] * sc + w * v2.z; acc[11] = acc[11] * sc + w * v2.w;
        acc[12] = acc[12] * sc + w * v3.x; acc[13] = acc[13] * sc + w * v3.y;
        acc[14] = acc[14] * sc + w * v3.z; acc[15] = acc[15] * sc + w * v3.w;
    }
    float inv = 1.f / fmaxf(den, 1e-16f);
    float o16[16];
#pragma unroll
    for (int j = 0; j < 16; ++j) {
        float a = acc[j] * inv;
        float b = __shfl_xor(a, 32, 64);
        o16[j] = 0.5f * (a + b);
    }
    float s0 = 0.f, s1 = 0.f;
    if (lane < 32) {
        const float* bp = bias + c0;
        const float* wa = Wrel + c0;
        const float* wb = Wroot + c0;
        float* op = out + (size_t)d * 512 + c0;
#pragma unroll
        for (int j = 0; j < 16; j += 4) {
            float4 bb = *(const float4*)(bp + j);
            float4 va = *(const float4*)(wa + j);
            float4 vb = *(const float4*)(wb + j);
            float4 r;
            r.x = fmaxf(o16[j + 0] + bb.x, 0.f);
            r.y = fmaxf(o16[j + 1] + bb.y, 0.f);
            r.z = fmaxf(o16[j + 2] + bb.z, 0.f);
            r.w = fmaxf(o16[j + 3] + bb.w, 0.f);
            *(float4*)(op + j) = r;
            s0 += r.x * va.x + r.y * va.y + r.z * va.z + r.w * va.w;
            s1 += r.x * vb.x + r.y * vb.y + r.z * vb.z + r.w * vb.w;
        }
    }
#pragma unroll
    for (int o = 16; o > 0; o >>= 1) {
        s0 += __shfl_xor(s0, o, 64);
        s1 += __shfl_xor(s1, o, 64);
    }
    if (lane == 0) { y0[d] = s0; y1[d] = s1; }
}

// ---------------- score via CSR scalar sums ----------------
__global__ void k_score2(const float* __restrict__ y0, const float* __restrict__ y1,
                         const int* __restrict__ rowptr, const int* __restrict__ csr_src,
                         const float* __restrict__ brel_p,
                         float* __restrict__ score, int N) {
    int d = blockIdx.x * blockDim.x + threadIdx.x;
    if (d >= N) return;
    float s = y1[d] + brel_p[0];
    int rs = rowptr[d], re = rowptr[d + 1];
    for (int e = rs; e < re; ++e) s += y0[csr_src[e]];
    score[d] = s;
}

// ---------------- per-graph top-k via radix select ----------------
__global__ __launch_bounds__(256) void k_topk_radix(const float* __restrict__ score, int ng, int k,
                                                    int* __restrict__ newidx, int* __restrict__ sel_old,
                                                    float* __restrict__ sel_scale) {
    int b = blockIdx.x;
    int t = threadIdx.x;
    __shared__ unsigned int keys[NG0];
    __shared__ int hist[256];
    __shared__ int scnt[256];
    __shared__ unsigned int s_pref, s_amask;
    __shared__ int s_krem, s_gt;
    for (int i = t; i < ng; i += 256) {
        float f = score[b * ng + i];
        unsigned int u = __float_as_uint(f);
        u = (u & 0x80000000u) ? ~u : (u | 0x80000000u);
        keys[i] = u;
        newidx[b * ng + i] = -1;
    }
    if (t == 0) { s_pref = 0u; s_amask = 0u; s_krem = k; s_gt = 0; }
    __syncthreads();
    for (int pass = 0; pass < 4; ++pass) {
        int shift = 24 - 8 * pass;
        hist[t] = 0;
        __syncthreads();
        unsigned int amask = s_amask, pref = s_pref;
        for (int i = t; i < ng; i += 256) {
            unsigned int u = keys[i];
            if ((u & amask) == pref) atomicAdd(&hist[(u >> shift) & 255], 1);
        }
        __syncthreads();
        if (t == 0) {
            int krem = s_krem, cum = 0, dsel = 0;
            for (int dd = 255; dd >= 0; --dd) {
                cum += hist[dd];
                if (cum >= krem) { dsel = dd; krem -= (cum - hist[dd]); break; }
            }
            s_pref = s_pref | ((unsigned int)dsel << shift);
            s_amask = s_amask | (0xFFu << shift);
            s_krem = krem;
        }
        __syncthreads();
    }
    unsigned int T = s_pref;
    int krem = s_krem;
    int chunk = (ng + 255) / 256;
    int lo = t * chunk, hi = min(ng, lo + chunk);
    int ceq = 0;
    for (int i = lo; i < hi; ++i) if (keys[i] == T) ceq++;
    scnt[t] = ceq;
    __syncthreads();
    for (int o = 1; o < 256; o <<= 1) {
        int add = (t >= o) ? scnt[t - o] : 0;
        __syncthreads();
        scnt[t] += add;
        __syncthreads();
    }
    int eq_rank = scnt[t] - ceq;
    for (int i = lo; i < hi; ++i) {
        unsigned int u = keys[i];
        int slot = -1;
        if (u > T) slot = atomicAdd(&s_gt, 1);
        else if (u == T) {
            if (eq_rank < krem) slot = (k - krem) + eq_rank;
            eq_rank++;
        }
        if (slot >= 0) {
            int oldg = b * ng + i;
            int newg = b * k + slot;
            newidx[oldg] = newg;
            sel_old[newg] = oldg;
            sel_scale[newg] = tanhf(score[oldg]);
        }
    }
}

// ---------------- pool gather + tanh scale + bf16 hi/lo split ----------------
__global__ __launch_bounds__(128) void k_pool_cvt(const float* __restrict__ x, const int* __restrict__ sel_old,
                                                  const float* __restrict__ sel_scale, float* __restrict__ xn,
                                                  __bf16* __restrict__ hi, __bf16* __restrict__ lo) {
    int nn = blockIdx.x;
    int so = sel_old[nn];
    float sc = sel_scale[nn];
    int c = threadIdx.x * 4;
    float4 vv = *(const float4*)(x + (size_t)so * 512 + c);
    vv.x *= sc; vv.y *= sc; vv.z *= sc; vv.w *= sc;
    *(float4*)(xn + (size_t)nn * 512 + c) = vv;
    float f[4] = {vv.x, vv.y, vv.z, vv.w};
    bf16x4 vh, vl;
#pragma unroll
    for (int j = 0; j < 4; ++j) {
        __bf16 hh = (__bf16)f[j];
        vh[j] = hh;
        vl[j] = (__bf16)(f[j] - (float)hh);
    }
    *(bf16x4*)(hi + (size_t)nn * 512 + c) = vh;
    *(bf16x4*)(lo + (size_t)nn * 512 + c) = vl;
}

// ---------------- readout phase 1 ----------------
__global__ __launch_bounds__(256) void k_readout_part(const float* __restrict__ x, int k,
                                                      float* __restrict__ pmax, float* __restrict__ psum) {
    int b = blockIdx.x, cg = blockIdx.y, rc = blockIdx.z;
    int t = threadIdx.x;
    int c4 = (t & 63);
    int rl = t >> 6;
    int col = cg * 256 + c4 * 4;
    int rstart = rc * 4 + rl;
    float4 mx = make_float4(-1e30f, -1e30f, -1e30f, -1e30f);
    float4 sm = make_float4(0.f, 0.f, 0.f, 0.f);
    for (int j = rstart; j < k; j += 32) {
        float4 v = *(const float4*)(x + ((size_t)(b * k + j)) * 512 + col);
        mx.x = fmaxf(mx.x, v.x); mx.y = fmaxf(mx.y, v.y); mx.z = fmaxf(mx.z, v.z); mx.w = fmaxf(mx.w, v.w);
        sm.x += v.x; sm.y += v.y; sm.z += v.z; sm.w += v.w;
    }
    __shared__ float lmx[256 * 4];
    __shared__ float lsm[256 * 4];
    int li = c4 * 4 + rl * 256;
    lmx[li + 0] = mx.x; lmx[li + 1] = mx.y; lmx[li + 2] = mx.z; lmx[li + 3] = mx.w;
    lsm[li + 0] = sm.x; lsm[li + 1] = sm.y; lsm[li + 2] = sm.z; lsm[li + 3] = sm.w;
    __syncthreads();
    if (rl == 0) {
        int ci = c4 * 4;
#pragma unroll
        for (int q = 0; q < 4; ++q) {
            float m = fmaxf(fmaxf(lmx[ci + q], lmx[ci + q + 256]), fmaxf(lmx[ci + q + 512], lmx[ci + q + 768]));
            float s = lsm[ci + q] + lsm[ci + q + 256] + lsm[ci + q + 512] + lsm[ci + q + 768];
            size_t o = ((size_t)(b * 8 + rc)) * 512 + col + q;
            pmax[o] = m;
            psum[o] = s;
        }
    }
}

// ---------------- readout phase 2 ----------------
__global__ __launch_bounds__(512) void k_readout_fin(const float* __restrict__ pmax, const float* __restrict__ psum,
                                                     int k, float* __restrict__ readout) {
    int b = blockIdx.x;
    int c = threadIdx.x;
    float m = -1e30f, s = 0.f;
#pragma unroll
    for (int rc = 0; rc < 8; ++rc) {
        size_t o = ((size_t)(b * 8 + rc)) * 512 + c;
        m = fmaxf(m, pmax[o]);
        s += psum[o];
    }
    readout[b * 1024 + c] += m;
    readout[b * 1024 + 512 + c] += s / (float)k;
}

// ---------------- MLP stages ----------------
__global__ __launch_bounds__(256) void k_mlp1(const float* __restrict__ readout, const float* __restrict__ W1t,
                                              const float* __restrict__ b1, float* __restrict__ h1) {
    int wid = (blockIdx.x * blockDim.x + threadIdx.x) >> 6;
    int lane = threadIdx.x & 63;
    int b = wid >> 9, col = wid & 511;
    const float* rp = readout + b * 1024 + lane * 16;
    const float* wp = W1t + (size_t)col * 1024 + lane * 16;
    float s = 0.f;
#pragma unroll
    for (int j = 0; j < 4; ++j) {
        float4 v = *(const float4*)(rp + j * 4);
        float4 w = *(const float4*)(wp + j * 4);
        s += v.x * w.x + v.y * w.y + v.z * w.z + v.w * w.w;
    }
#pragma unroll
    for (int o = 32; o > 0; o >>= 1) s += __shfl_xor(s, o, 64);
    if (lane == 0) h1[b * 512 + col] = fmaxf(s + b1[col], 0.f);
}

__global__ __launch_bounds__(256) void k_mlp2(const float* __restrict__ h1, const float* __restrict__ W2t,
                                              const float* __restrict__ b2, float* __restrict__ h2) {
    int wid = (blockIdx.x * blockDim.x + threadIdx.x) >> 6;
    int lane = threadIdx.x & 63;
    int b = wid >> 8, col = wid & 255;
    const float* hp = h1 + b * 512 + lane * 8;
    const float* wp = W2t + (size_t)col * 512 + lane * 8;
    float s = 0.f;
#pragma unroll
    for (int j = 0; j < 2; ++j) {
        float4 v = *(const float4*)(hp + j * 4);
        float4 w = *(const float4*)(wp + j * 4);
        s += v.x * w.x + v.y * w.y + v.z * w.z + v.w * w.w;
    }
#pragma unroll
    for (int o = 32; o > 0; o >>= 1) s += __shfl_xor(s, o, 64);
    if (lane == 0) h2[b * 256 + col] = fmaxf(s + b2[col], 0.f);
}

__global__ __launch_bounds__(256) void k_mlp3(const float* __restrict__ h2, const float* __restrict__ W3,
                                              const float* __restrict__ b3, float* __restrict__ out) {
    int b = threadIdx.x >> 6;
    int lane = threadIdx.x & 63;
    float hv[4];
    int idx[4];
#pragma unroll
    for (int j = 0; j < 4; ++j) { idx[j] = lane + j * 64; hv[j] = h2[b * 256 + idx[j]]; }
    float lg[5];
#pragma unroll
    for (int q = 0; q < 5; ++q) {
        float p = 0.f;
#pragma unroll
        for (int j = 0; j < 4; ++j) p += hv[j] * W3[idx[j] * 5 + q];
#pragma unroll
        for (int o = 32; o > 0; o >>= 1) p += __shfl_xor(p, o, 64);
        lg[q] = p + b3[q];
    }
    if (lane == 0) {
        float m = lg[0];
#pragma unroll
        for (int q = 1; q < 5; ++q) m = fmaxf(m, lg[q]);
        float den = 0.f;
#pragma unroll
        for (int q = 0; q < 5; ++q) den += __expf(lg[q] - m);
#pragma unroll
        for (int q = 0; q < 5; ++q) {
            out[b * 5 + q] = lg[q];
            out[NB * 5 + b * 5 + q] = __expf(lg[q] - m) / den;
        }
    }
}

extern "C" void kernel_launch(void* const* d_in, const int* in_sizes, int n_in,
                              void* d_out, int out_size, void* d_ws, size_t ws_size,
                              hipStream_t stream) {
    const float* x0    = (const float*)d_in[0];
    const int*   ei    = (const int*)d_in[1];
    const float* gWl   = (const float*)d_in[2];
    const float* gbl   = (const float*)d_in[3];
    const float* gWr   = (const float*)d_in[4];
    const float* gbr   = (const float*)d_in[5];
    const float* gatt  = (const float*)d_in[6];
    const float* gbias = (const float*)d_in[7];
    const float* sWrel = (const float*)d_in[8];
    const float* sbrel = (const float*)d_in[9];
    const float* sWroot= (const float*)d_in[10];
    const float* W1 = (const float*)d_in[11];
    const float* b1 = (const float*)d_in[12];
    const float* W2 = (const float*)d_in[13];
    const float* b2 = (const float*)d_in[14];
    const float* W3 = (const float*)d_in[15];
    const float* b3 = (const float*)d_in[16];
    float* out = (float*)d_out;

    char* base = (char*)d_ws;
    size_t off = 0;
    auto alloc = [&](size_t bytes) -> void* {
        void* p = base + off;
        off += (bytes + 255) & ~(size_t)255;
        return p;
    };
    int*   s_src   = (int*)alloc((size_t)ETOT * 4);
    int*   s_dst   = (int*)alloc((size_t)ETOT * 4);
    int*   s_mask  = (int*)alloc((size_t)ETOT * 4);
    int*   csr_src = (int*)alloc((size_t)ETOT * 4);
    int*   rowptr  = (int*)alloc((size_t)(h_Ns[0] + 1) * 4);
    int*   cnt     = (int*)alloc((size_t)(h_Ns[0] + 1) * 4);
    float* score   = (float*)alloc((size_t)h_Ns[0] * 4);
    int*   newidx  = (int*)alloc((size_t)h_Ns[0] * 4);
    int*   sel_old = (int*)alloc((size_t)7000 * 4);
    float* sel_scale = (float*)alloc((size_t)7000 * 4);
    float* readout = (float*)alloc((size_t)NB * 1024 * 4);
    float* pmax    = (float*)alloc((size_t)NB * 8 * 512 * 4);
    float* psum    = (float*)alloc((size_t)NB * 8 * 512 * 4);
    float* y0      = (float*)alloc((size_t)h_Ns[0] * 4);
    float* y1      = (float*)alloc((size_t)h_Ns[0] * 4);
    float* xlr     = (float*)alloc((size_t)h_Ns[0] * 2048 * 4);
    float* gatout  = (float*)alloc((size_t)h_Ns[0] * 512 * 4);
    float* xpool   = (float*)alloc((size_t)7000 * 512 * 4);
    __bf16* Ah     = (__bf16*)alloc((size_t)h_Ns[0] * 512 * 2);
    __bf16* Al     = (__bf16*)alloc((size_t)h_Ns[0] * 512 * 2);
    __bf16* WtH    = (__bf16*)alloc((size_t)8 * 1024 * 512 * 2);
    __bf16* WtL    = (__bf16*)alloc((size_t)8 * 1024 * 512 * 2);
    float* biasC   = (float*)alloc((size_t)4 * 2048 * 4);
    float* W1t     = (float*)alloc((size_t)512 * 1024 * 4);
    float* W2t     = (float*)alloc((size_t)256 * 512 * 4);
    float* h1b     = (float*)alloc((size_t)NB * 512 * 4);
    float* h2b     = (float*)alloc((size_t)NB * 256 * 4);

    hipMemsetAsync(readout, 0, (size_t)NB * 1024 * 4, stream);
    k_cvtWt<<<dim3(32, 16, 8), dim3(32, 8), 0, stream>>>(gWl, gWr, WtH, WtL);
    k_cvtA<<<(h_Ns[0] * 512 / 8 + 255) / 256, 256, 0, stream>>>(x0, Ah, Al, h_Ns[0] * 512);
    k_prep_bias<<<(4 * 2048 + 255) / 256, 256, 0, stream>>>(gbl, gbr, biasC);
    k_transpose<<<dim3(16, 32), dim3(32, 8), 0, stream>>>(W1, W1t, 1024, 512);
    k_transpose<<<dim3(8, 16), dim3(32, 8), 0, stream>>>(W2, W2t, 512, 256);

    for (int i = 0; i < 4; ++i) {
        int N = h_Ns[i], ng = h_ngs[i], k = h_ks[i];
        // CSR by dst (remap fused into hist for i>0)
        hipMemsetAsync(cnt, 0, (size_t)(N + 1) * 4, stream);
        if (i == 0)
            k_init_hist<<<(ETOT + 255) / 256, 256, 0, stream>>>(ei, s_src, s_dst, s_mask, cnt);
        else
            k_remap_hist<<<(ETOT + 255) / 256, 256, 0, stream>>>(s_src, s_dst, s_mask, newidx, cnt);
        k_scan<<<1, 1024, 0, stream>>>(cnt, rowptr, N);
        k_scatter<<<(ETOT + 255) / 256, 256, 0, stream>>>(s_dst, s_src, s_mask, cnt, csr_src);
        // combined xl|xr GEMM (bf16x3 MFMA via global_load_lds, swizzled LDS)
        int nRows = (N + 127) >> 7;
        k_gemm3<<<nRows * 16, 256, 0, stream>>>(Ah, Al, WtH + (size_t)(2 * i) * 1024 * 512, WtL + (size_t)(2 * i) * 1024 * 512,
                                                biasC + (size_t)i * 2048, xlr, N, 2048);
        // fused GAT (wave per node) + SAG row-dot epilogue
        k_gat_wave<<<(N + 3) / 4, 256, 0, stream>>>(xlr, rowptr, csr_src, gatt + (size_t)i * 1024,
                                                    gbias + (size_t)i * 512, sWrel + (size_t)i * 512,
                                                    sWroot + (size_t)i * 512, gatout, y0, y1, N);
        k_score2<<<(N + 255) / 256, 256, 0, stream>>>(y0, y1, rowptr, csr_src, sbrel + i, score, N);
        // top-k per graph
        k_topk_radix<<<NB, 256, 0, stream>>>(score, ng, k, newidx, sel_old, sel_scale);
        // pool gather + bf16 split for next layer
        k_pool_cvt<<<NB * k, 128, 0, stream>>>(gatout, sel_old, sel_scale, xpool, Ah, Al);
        // readout
        k_readout_part<<<dim3(NB, 2, 8), 256, 0, stream>>>(xpool, k, pmax, psum);
        k_readout_fin<<<NB, 512, 0, stream>>>(pmax, psum, k, readout);
    }
    // MLP head
    k_mlp1<<<512, 256, 0, stream>>>(readout, W1t, b1, h1b);
    k_mlp2<<<256, 256, 0, stream>>>(h1b, W2t, b2, h2b);
    k_mlp3<<<1, 256, 0, stream>>>(h2b, W3, b3, out);
}